// Round 4
// baseline (389.404 us; speedup 1.0000x reference)
//
#include <hip/hip_runtime.h>
#include <hip/hip_bf16.h>
#include <hip/hip_fp16.h>
#include <math.h>

#define NEG_SLOPE 0.2f

typedef __attribute__((ext_vector_type(8))) short bf16x8_t;
typedef __attribute__((ext_vector_type(4))) float f32x4_t;

struct __align__(8) half4_t { __half2 a, b; };

// ---------------------------------------------------------------------------
// CSR build: histogram -> block scan -> scatter fill
// ---------------------------------------------------------------------------
__global__ void hist_k(const int* __restrict__ ei, int E, int n, int* __restrict__ deg) {
    int e = blockIdx.x * 256 + threadIdx.x;
    int ET = E + n;
    if (e >= ET) return;
    int d = (e < E) ? ei[E + e] : (e - E);
    atomicAdd(&deg[d], 1);
}

__global__ void scan1_k(const int* __restrict__ deg, int* __restrict__ incl,
                        int* __restrict__ bsums, int n) {
    __shared__ int s[256];
    int tid = threadIdx.x;
    int i = blockIdx.x * 256 + tid;
    int v = (i < n) ? deg[i] : 0;
    s[tid] = v;
    __syncthreads();
    for (int off = 1; off < 256; off <<= 1) {
        int t = (tid >= off) ? s[tid - off] : 0;
        __syncthreads();
        s[tid] += t;
        __syncthreads();
    }
    if (i < n) incl[i] = s[tid];
    if (tid == 255) bsums[blockIdx.x] = s[255];
}

__global__ void scan2_k(int* __restrict__ bsums, int nch) {
    __shared__ int s[256];
    int tid = threadIdx.x;
    int v = (tid < nch) ? bsums[tid] : 0;
    int orig = v;
    s[tid] = v;
    __syncthreads();
    for (int off = 1; off < 256; off <<= 1) {
        int t = (tid >= off) ? s[tid - off] : 0;
        __syncthreads();
        s[tid] += t;
        __syncthreads();
    }
    if (tid < nch) bsums[tid] = s[tid] - orig;  // exclusive
}

__global__ void scan3_k(int* __restrict__ offsets, int* __restrict__ cursor,
                        const int* __restrict__ bsums, int n, int total) {
    int i = blockIdx.x * 256 + threadIdx.x;
    if (i < n) {
        int excl = offsets[i] - cursor[i] + bsums[i >> 8];
        offsets[i] = excl;
        cursor[i]  = excl;
    }
    if (i == 0 && blockIdx.x == 0) offsets[n] = total;
}

__global__ void fill_k(const int* __restrict__ ei, int E, int n,
                       int* __restrict__ cursor, int* __restrict__ csr) {
    int e = blockIdx.x * 256 + threadIdx.x;
    int ET = E + n;
    if (e >= ET) return;
    int s, d;
    if (e < E) { s = ei[e]; d = ei[E + e]; }
    else       { s = e - E; d = e - E; }
    int pos = atomicAdd(&cursor[d], 1);
    csr[pos] = s;
}

// ---------------------------------------------------------------------------
// fp32 -> bf16 hi/lo split helpers
// ---------------------------------------------------------------------------
__device__ inline void bf16_split(float f, ushort& hi, ushort& lo) {
    unsigned int u = __float_as_uint(f);
    unsigned int r = u + 0x7FFFu + ((u >> 16) & 1u);
    hi = (ushort)(r >> 16);
    float back = __uint_as_float((unsigned int)hi << 16);
    float rem = f - back;
    unsigned int u2 = __float_as_uint(rem);
    unsigned int r2 = u2 + 0x7FFFu + ((u2 >> 16) & 1u);
    lo = (ushort)(r2 >> 16);
}

// A [M,K] fp32 -> Ah, Al [M,K] bf16 (row-major), 8 elems/thread
__global__ void splitA_k(const float* __restrict__ A, ushort* __restrict__ Ah,
                         ushort* __restrict__ Al, long total8) {
    long i = (long)blockIdx.x * 256 + threadIdx.x;
    if (i >= total8) return;
    const float* src = A + i * 8;
    float4 a = *(const float4*)src;
    float4 b = *(const float4*)(src + 4);
    float fv[8] = {a.x, a.y, a.z, a.w, b.x, b.y, b.z, b.w};
    ushort hv[8], lv[8];
#pragma unroll
    for (int q = 0; q < 8; q++) bf16_split(fv[q], hv[q], lv[q]);
    *(bf16x8_t*)(Ah + i * 8) = *(bf16x8_t*)hv;
    *(bf16x8_t*)(Al + i * 8) = *(bf16x8_t*)lv;
}

// W [K,N] fp32 -> WhT, WlT [N,K] bf16 (transposed)
__global__ void splitWT_k(const float* __restrict__ W, ushort* __restrict__ WhT,
                          ushort* __restrict__ WlT, int K, int N) {
    int idx = blockIdx.x * 256 + threadIdx.x;
    if (idx >= K * N) return;
    int k = idx / N, n = idx - k * N;
    ushort hi, lo;
    bf16_split(W[idx], hi, lo);
    WhT[(size_t)n * K + k] = hi;
    WlT[(size_t)n * K + k] = lo;
}

// ---------------------------------------------------------------------------
// split-bf16 MFMA GEMM, presplit inputs, fused attention-prep epilogue.
// A: Ah/Al [M,K] bf16.  B: BhT/BlT [Nc,K] bf16 (transposed).
// Writes Ch fp16 [M,Nc]; atomically accumulates asb[i]=h[i,:]·a_src,
// adb[i]=h[i,:]·a_dst.
// block tile 128x64, 4 waves (2 in M x 2 in N), wave tile 64x32, BK=32.
// ---------------------------------------------------------------------------
__global__ __launch_bounds__(256) void gemm_k(const ushort* __restrict__ Ah,
                                              const ushort* __restrict__ Al,
                                              const ushort* __restrict__ BhT,
                                              const ushort* __restrict__ BlT,
                                              __half* __restrict__ Ch,
                                              float* __restrict__ asb,
                                              float* __restrict__ adb,
                                              const float* __restrict__ a_src,
                                              const float* __restrict__ a_dst,
                                              int M, int K, int Nc) {
    __shared__ __align__(16) ushort sAh[128][40];
    __shared__ __align__(16) ushort sAl[128][40];
    __shared__ __align__(16) ushort sBh[64][40];
    __shared__ __align__(16) ushort sBl[64][40];

    const int tid  = threadIdx.x;
    const int lane = tid & 63;
    const int wv   = tid >> 6;
    const int wm   = wv & 1, wn = wv >> 1;
    const int m0   = blockIdx.x << 7;
    const int n0   = blockIdx.y << 6;

    f32x4_t acc[4][2];
#pragma unroll
    for (int i = 0; i < 4; i++)
#pragma unroll
        for (int j = 0; j < 2; j++) acc[i][j] = (f32x4_t){0.f, 0.f, 0.f, 0.f};

    const int arow = tid >> 1;          // 0..127
    const int acb  = (tid & 1) << 4;    // 0 / 16
    const int brow = tid >> 2;          // 0..63
    const int bkb  = (tid & 3) << 3;    // 0,8,16,24

    const bf16x8_t zv = {};

    for (int k0 = 0; k0 < K; k0 += 32) {
        // ---- stage A (bf16, no conversion) ----
        {
            const int gr = m0 + arow;
            bf16x8_t h0 = zv, h1 = zv, l0 = zv, l1 = zv;
            if (gr < M) {
                const ushort* ph = Ah + (size_t)gr * K + k0 + acb;
                const ushort* pl = Al + (size_t)gr * K + k0 + acb;
                h0 = *(const bf16x8_t*)ph;
                h1 = *(const bf16x8_t*)(ph + 8);
                l0 = *(const bf16x8_t*)pl;
                l1 = *(const bf16x8_t*)(pl + 8);
            }
            *(bf16x8_t*)&sAh[arow][acb]     = h0;
            *(bf16x8_t*)&sAh[arow][acb + 8] = h1;
            *(bf16x8_t*)&sAl[arow][acb]     = l0;
            *(bf16x8_t*)&sAl[arow][acb + 8] = l1;
        }
        // ---- stage B (already transposed) ----
        {
            const ushort* ph = BhT + (size_t)(n0 + brow) * K + k0 + bkb;
            const ushort* pl = BlT + (size_t)(n0 + brow) * K + k0 + bkb;
            *(bf16x8_t*)&sBh[brow][bkb] = *(const bf16x8_t*)ph;
            *(bf16x8_t*)&sBl[brow][bkb] = *(const bf16x8_t*)pl;
        }
        __syncthreads();
        // ---- MFMA: Ahi*Bhi + Ahi*Blo + Alo*Bhi ----
        bf16x8_t ah[4], al[4], bh[2], bl[2];
        const int rbase = (wm << 6) + (lane & 15);
        const int slot  = (lane >> 4) << 3;
#pragma unroll
        for (int mi = 0; mi < 4; mi++) {
            ah[mi] = *(const bf16x8_t*)&sAh[rbase + (mi << 4)][slot];
            al[mi] = *(const bf16x8_t*)&sAl[rbase + (mi << 4)][slot];
        }
        const int cbase = (wn << 5) + (lane & 15);
#pragma unroll
        for (int ni = 0; ni < 2; ni++) {
            bh[ni] = *(const bf16x8_t*)&sBh[cbase + (ni << 4)][slot];
            bl[ni] = *(const bf16x8_t*)&sBl[cbase + (ni << 4)][slot];
        }
#pragma unroll
        for (int mi = 0; mi < 4; mi++)
#pragma unroll
            for (int ni = 0; ni < 2; ni++) {
                acc[mi][ni] = __builtin_amdgcn_mfma_f32_16x16x32_bf16(ah[mi], bh[ni], acc[mi][ni], 0, 0, 0);
                acc[mi][ni] = __builtin_amdgcn_mfma_f32_16x16x32_bf16(ah[mi], bl[ni], acc[mi][ni], 0, 0, 0);
                acc[mi][ni] = __builtin_amdgcn_mfma_f32_16x16x32_bf16(al[mi], bh[ni], acc[mi][ni], 0, 0, 0);
            }
        __syncthreads();
    }

    // ---- epilogue: C/D layout col=lane&15, row=(lane>>4)*4+reg ----
    const int col0 = n0 + (wn << 5) + (lane & 15);
    const float asv0 = a_src[col0],      adv0 = a_dst[col0];
    const float asv1 = a_src[col0 + 16], adv1 = a_dst[col0 + 16];

#pragma unroll
    for (int mi = 0; mi < 4; mi++) {
        const int row0 = m0 + (wm << 6) + (mi << 4) + ((lane >> 4) << 2);
        // fp16 store
#pragma unroll
        for (int ni = 0; ni < 2; ni++) {
            const int col = col0 + (ni << 4);
#pragma unroll
            for (int r = 0; r < 4; r++)
                if (row0 + r < M)
                    Ch[(size_t)(row0 + r) * Nc + col] = __float2half(acc[mi][ni][r]);
        }
        // fused attention prep: per-row partial dot over this block's 32 cols
        float ss[4], sd[4];
#pragma unroll
        for (int r = 0; r < 4; r++) {
            ss[r] = acc[mi][0][r] * asv0 + acc[mi][1][r] * asv1;
            sd[r] = acc[mi][0][r] * adv0 + acc[mi][1][r] * adv1;
        }
#pragma unroll
        for (int off = 1; off < 16; off <<= 1) {
#pragma unroll
            for (int r = 0; r < 4; r++) {
                ss[r] += __shfl_xor(ss[r], off);
                sd[r] += __shfl_xor(sd[r], off);
            }
        }
        if ((lane & 15) == 0) {
#pragma unroll
            for (int r = 0; r < 4; r++)
                if (row0 + r < M) {
                    atomicAdd(&asb[row0 + r], ss[r]);
                    atomicAdd(&adb[row0 + r], sd[r]);
                }
        }
    }
}

// ---------------------------------------------------------------------------
// fused per-node softmax + aggregation (wave per node), fp16 h gather.
// SPLIT_OUT: write result as bf16 hi/lo (next layer's GEMM A input);
// else fp32.
// ---------------------------------------------------------------------------
#define DEG_CAP 128

template <int D, bool DO_ELU, bool SPLIT_OUT>
__global__ __launch_bounds__(256) void agg_k(const int* __restrict__ offs,
                                             const int* __restrict__ csr,
                                             const float* __restrict__ asb,
                                             const float* __restrict__ adb,
                                             const __half* __restrict__ h,
                                             const float* __restrict__ bias,
                                             float* __restrict__ out,
                                             ushort* __restrict__ oh,
                                             ushort* __restrict__ ol, int n) {
    __shared__ float wsh[4][DEG_CAP];
    __shared__ int   jsh[4][DEG_CAP];
    const int wv   = threadIdx.x >> 6;
    const int lane = threadIdx.x & 63;
    const int wid  = (blockIdx.x << 2) + wv;
    const bool active = wid < n;

    int beg = 0, deg = 0;
    float adi = 0.f;
    if (active) {
        beg = offs[wid];
        deg = offs[wid + 1] - beg;
        adi = adb[wid];
    }
    const int degc = deg < DEG_CAP ? deg : DEG_CAP;

    float m = -INFINITY;
    if (active) {
        for (int e = lane; e < degc; e += 64) {
            int j = csr[beg + e];
            float v = asb[j] + adi;
            v = v > 0.f ? v : NEG_SLOPE * v;
            jsh[wv][e] = j;
            wsh[wv][e] = v;
            m = fmaxf(m, v);
        }
        for (int e = DEG_CAP + lane; e < deg; e += 64) {
            float v = asb[csr[beg + e]] + adi;
            v = v > 0.f ? v : NEG_SLOPE * v;
            m = fmaxf(m, v);
        }
#pragma unroll
        for (int o = 32; o; o >>= 1) m = fmaxf(m, __shfl_xor(m, o));
    }

    float inv = 0.f;
    if (active) {
        float ssum = 0.f;
        for (int e = lane; e < degc; e += 64) {
            float ww = __expf(wsh[wv][e] - m);
            wsh[wv][e] = ww;
            ssum += ww;
        }
        for (int e = DEG_CAP + lane; e < deg; e += 64) {
            float v = asb[csr[beg + e]] + adi;
            v = v > 0.f ? v : NEG_SLOPE * v;
            ssum += __expf(v - m);
        }
#pragma unroll
        for (int o = 32; o; o >>= 1) ssum += __shfl_xor(ssum, o);
        inv = 1.f / ssum;
    }

    __syncthreads();

    if (!active) return;

    constexpr int U = D / 64;  // 4 (D=256) or 1 (D=64)
    float a0[U] = {}, a1[U] = {}, a2[U] = {}, a3[U] = {};

    int e = 0;
    for (; e + 4 <= degc; e += 4) {
        int j0 = jsh[wv][e], j1 = jsh[wv][e + 1], j2 = jsh[wv][e + 2], j3 = jsh[wv][e + 3];
        float w0 = wsh[wv][e], w1 = wsh[wv][e + 1], w2 = wsh[wv][e + 2], w3 = wsh[wv][e + 3];
        if constexpr (U == 4) {
            const half4_t h0 = *(const half4_t*)(h + (size_t)j0 * D + (lane << 2));
            const half4_t h1 = *(const half4_t*)(h + (size_t)j1 * D + (lane << 2));
            const half4_t h2 = *(const half4_t*)(h + (size_t)j2 * D + (lane << 2));
            const half4_t h3 = *(const half4_t*)(h + (size_t)j3 * D + (lane << 2));
            float2 f0a = __half22float2(h0.a), f0b = __half22float2(h0.b);
            float2 f1a = __half22float2(h1.a), f1b = __half22float2(h1.b);
            float2 f2a = __half22float2(h2.a), f2b = __half22float2(h2.b);
            float2 f3a = __half22float2(h3.a), f3b = __half22float2(h3.b);
            a0[0] = fmaf(w0, f0a.x, a0[0]); a0[1] = fmaf(w0, f0a.y, a0[1]);
            a0[2] = fmaf(w0, f0b.x, a0[2]); a0[3] = fmaf(w0, f0b.y, a0[3]);
            a1[0] = fmaf(w1, f1a.x, a1[0]); a1[1] = fmaf(w1, f1a.y, a1[1]);
            a1[2] = fmaf(w1, f1b.x, a1[2]); a1[3] = fmaf(w1, f1b.y, a1[3]);
            a2[0] = fmaf(w2, f2a.x, a2[0]); a2[1] = fmaf(w2, f2a.y, a2[1]);
            a2[2] = fmaf(w2, f2b.x, a2[2]); a2[3] = fmaf(w2, f2b.y, a2[3]);
            a3[0] = fmaf(w3, f3a.x, a3[0]); a3[1] = fmaf(w3, f3a.y, a3[1]);
            a3[2] = fmaf(w3, f3b.x, a3[2]); a3[3] = fmaf(w3, f3b.y, a3[3]);
        } else {
            a0[0] = fmaf(w0, __half2float(h[(size_t)j0 * D + lane]), a0[0]);
            a1[0] = fmaf(w1, __half2float(h[(size_t)j1 * D + lane]), a1[0]);
            a2[0] = fmaf(w2, __half2float(h[(size_t)j2 * D + lane]), a2[0]);
            a3[0] = fmaf(w3, __half2float(h[(size_t)j3 * D + lane]), a3[0]);
        }
    }
    for (; e < degc; ++e) {
        int j = jsh[wv][e];
        float ww = wsh[wv][e];
        if constexpr (U == 4) {
            const half4_t hv = *(const half4_t*)(h + (size_t)j * D + (lane << 2));
            float2 fa = __half22float2(hv.a), fb = __half22float2(hv.b);
            a0[0] = fmaf(ww, fa.x, a0[0]); a0[1] = fmaf(ww, fa.y, a0[1]);
            a0[2] = fmaf(ww, fb.x, a0[2]); a0[3] = fmaf(ww, fb.y, a0[3]);
        } else {
            a0[0] = fmaf(ww, __half2float(h[(size_t)j * D + lane]), a0[0]);
        }
    }
    for (int eo = DEG_CAP; eo < deg; ++eo) {
        int j = csr[beg + eo];
        float v = asb[j] + adi;
        v = v > 0.f ? v : NEG_SLOPE * v;
        float ww = __expf(v - m);
        if constexpr (U == 4) {
            const half4_t hv = *(const half4_t*)(h + (size_t)j * D + (lane << 2));
            float2 fa = __half22float2(hv.a), fb = __half22float2(hv.b);
            a0[0] = fmaf(ww, fa.x, a0[0]); a0[1] = fmaf(ww, fa.y, a0[1]);
            a0[2] = fmaf(ww, fb.x, a0[2]); a0[3] = fmaf(ww, fb.y, a0[3]);
        } else {
            a0[0] = fmaf(ww, __half2float(h[(size_t)j * D + lane]), a0[0]);
        }
    }

    if constexpr (U == 4) {
        float t[4];
#pragma unroll
        for (int u = 0; u < 4; u++) {
            float v = (a0[u] + a1[u] + a2[u] + a3[u]) * inv + bias[(lane << 2) + u];
            if (DO_ELU) v = v > 0.f ? v : expm1f(v);
            t[u] = v;
        }
        if constexpr (SPLIT_OUT) {
            ushort hv[4], lv[4];
#pragma unroll
            for (int u = 0; u < 4; u++) bf16_split(t[u], hv[u], lv[u]);
            *(ushort4*)(oh + (size_t)wid * D + (lane << 2)) = make_ushort4(hv[0], hv[1], hv[2], hv[3]);
            *(ushort4*)(ol + (size_t)wid * D + (lane << 2)) = make_ushort4(lv[0], lv[1], lv[2], lv[3]);
        } else {
            *(float4*)(out + (size_t)wid * D + (lane << 2)) = make_float4(t[0], t[1], t[2], t[3]);
        }
    } else {
        float t = (a0[0] + a1[0] + a2[0] + a3[0]) * inv + bias[lane];
        if (DO_ELU) t = t > 0.f ? t : expm1f(t);
        out[(size_t)wid * D + lane] = t;
    }
}

// ---------------------------------------------------------------------------
// layer 3: h3 = out2 @ W3 (64->1) fused with logit pieces
// ---------------------------------------------------------------------------
__global__ void l3_prep_k(const float* __restrict__ o2, const float* __restrict__ W3,
                          const float* __restrict__ as3, const float* __restrict__ ad3,
                          float* __restrict__ h3, float* __restrict__ asb,
                          float* __restrict__ adb, int n) {
    int wid = (blockIdx.x << 2) + (threadIdx.x >> 6);
    int lane = threadIdx.x & 63;
    if (wid >= n) return;
    float t = o2[(size_t)wid * 64 + lane] * W3[lane];
#pragma unroll
    for (int o = 32; o; o >>= 1) t += __shfl_xor(t, o);
    if (lane == 0) {
        h3[wid]  = t;
        asb[wid] = t * as3[0];
        adb[wid] = t * ad3[0];
    }
}

__global__ void agg3_k(const int* __restrict__ offs, const int* __restrict__ csr,
                       const float* __restrict__ asb, const float* __restrict__ adb,
                       const float* __restrict__ h3, const float* __restrict__ b3,
                       float* __restrict__ out, int n) {
    int wid = (blockIdx.x << 2) + (threadIdx.x >> 6);
    int lane = threadIdx.x & 63;
    if (wid >= n) return;
    int beg = offs[wid], end = offs[wid + 1];
    float adi = adb[wid];

    float m = -INFINITY;
    for (int e = beg + lane; e < end; e += 64) {
        float v = asb[csr[e]] + adi;
        v = v > 0.f ? v : NEG_SLOPE * v;
        m = fmaxf(m, v);
    }
#pragma unroll
    for (int o = 32; o; o >>= 1) m = fmaxf(m, __shfl_xor(m, o));

    float ssum = 0.f, acc = 0.f;
    for (int e = beg + lane; e < end; e += 64) {
        int j = csr[e];
        float v = asb[j] + adi;
        v = v > 0.f ? v : NEG_SLOPE * v;
        float w = __expf(v - m);
        ssum += w;
        acc = fmaf(w, h3[j], acc);
    }
#pragma unroll
    for (int o = 32; o; o >>= 1) {
        ssum += __shfl_xor(ssum, o);
        acc  += __shfl_xor(acc, o);
    }
    if (lane == 0) out[wid] = acc / ssum + b3[0];
}

// ---------------------------------------------------------------------------
extern "C" void kernel_launch(void* const* d_in, const int* in_sizes, int n_in,
                              void* d_out, int out_size, void* d_ws, size_t ws_size,
                              hipStream_t stream) {
    const float* x   = (const float*)d_in[0];
    const int*   ei  = (const int*)d_in[1];
    const float* W1  = (const float*)d_in[2];
    const float* as1 = (const float*)d_in[3];
    const float* ad1 = (const float*)d_in[4];
    const float* b1  = (const float*)d_in[5];
    const float* W2  = (const float*)d_in[6];
    const float* as2 = (const float*)d_in[7];
    const float* ad2 = (const float*)d_in[8];
    const float* b2  = (const float*)d_in[9];
    const float* W3  = (const float*)d_in[10];
    const float* as3 = (const float*)d_in[11];
    const float* ad3 = (const float*)d_in[12];
    const float* b3  = (const float*)d_in[13];

    const int d1 = in_sizes[3];                    // 256
    const int C  = in_sizes[2] / d1;               // 128
    const int N  = in_sizes[0] / C;                // 50000
    const int E  = in_sizes[1] / 2;                // 800000
    const int d2 = in_sizes[7];                    // 64
    const int ET = E + N;                          // 850000

    char* p = (char*)d_ws;
    auto alloc = [&](size_t bytes) -> void* {
        void* q = (void*)p;
        p += (bytes + 255) & ~(size_t)255;
        return q;
    };
    int*    offsets = (int*)alloc(sizeof(int) * (size_t)(N + 1));
    int*    cursor  = (int*)alloc(sizeof(int) * (size_t)N);
    int*    bsums   = (int*)alloc(sizeof(int) * 256);
    int*    csr     = (int*)alloc(sizeof(int) * (size_t)ET);
    float*  alpha   = (float*)alloc(sizeof(float) * (size_t)4 * N);  // as1b,ad1b,as2b,ad2b
    float*  as1b = alpha, *ad1b = alpha + N, *as2b = alpha + 2 * N, *ad2b = alpha + 3 * N;
    ushort* xh      = (ushort*)alloc(sizeof(ushort) * (size_t)N * C);
    ushort* xl      = (ushort*)alloc(sizeof(ushort) * (size_t)N * C);
    ushort* w1h     = (ushort*)alloc(sizeof(ushort) * (size_t)C * d1);
    ushort* w1l     = (ushort*)alloc(sizeof(ushort) * (size_t)C * d1);
    ushort* w2h     = (ushort*)alloc(sizeof(ushort) * (size_t)d1 * d2);
    ushort* w2l     = (ushort*)alloc(sizeof(ushort) * (size_t)d1 * d2);
    __half* ch1     = (__half*)alloc(sizeof(__half) * (size_t)N * d1);
    ushort* o1h     = (ushort*)alloc(sizeof(ushort) * (size_t)N * d1);
    ushort* o1l     = (ushort*)alloc(sizeof(ushort) * (size_t)N * d1);
    __half* ch2     = (__half*)alloc(sizeof(__half) * (size_t)N * d2);
    float*  o2      = (float*)alloc(sizeof(float) * (size_t)N * d2);
    float*  h3      = (float*)alloc(sizeof(float) * (size_t)N);
    float*  as3b    = (float*)alloc(sizeof(float) * (size_t)N);
    float*  ad3b    = (float*)alloc(sizeof(float) * (size_t)N);

    const int eb  = (ET + 255) / 256;
    const int nch = (N + 255) / 256;
    const int wb  = (N + 3) / 4;

    // ---- zero accumulators ----
    hipMemsetAsync(cursor, 0, sizeof(int) * (size_t)N, stream);
    hipMemsetAsync(alpha, 0, sizeof(float) * (size_t)4 * N, stream);

    // ---- CSR build ----
    hist_k<<<eb, 256, 0, stream>>>(ei, E, N, cursor);
    scan1_k<<<nch, 256, 0, stream>>>(cursor, offsets, bsums, N);
    scan2_k<<<1, 256, 0, stream>>>(bsums, nch);
    scan3_k<<<nch, 256, 0, stream>>>(offsets, cursor, bsums, N, ET);
    fill_k<<<eb, 256, 0, stream>>>(ei, E, N, cursor, csr);

    // ---- presplit inputs & weights ----
    {
        long t8 = (long)N * C / 8;
        splitA_k<<<(int)((t8 + 255) / 256), 256, 0, stream>>>(x, xh, xl, t8);
        splitWT_k<<<(C * d1 + 255) / 256, 256, 0, stream>>>(W1, w1h, w1l, C, d1);
        splitWT_k<<<(d1 * d2 + 255) / 256, 256, 0, stream>>>(W2, w2h, w2l, d1, d2);
    }

    // ---- layer 1: 128 -> 256, ELU ----
    {
        dim3 g((N + 127) / 128, d1 / 64);
        gemm_k<<<g, 256, 0, stream>>>(xh, xl, w1h, w1l, ch1, as1b, ad1b, as1, ad1, N, C, d1);
        agg_k<256, true, true><<<wb, 256, 0, stream>>>(offsets, csr, as1b, ad1b, ch1, b1,
                                                       nullptr, o1h, o1l, N);
    }
    // ---- layer 2: 256 -> 64, ELU ----
    {
        dim3 g((N + 127) / 128, d2 / 64);
        gemm_k<<<g, 256, 0, stream>>>(o1h, o1l, w2h, w2l, ch2, as2b, ad2b, as2, ad2, N, d1, d2);
        agg_k<64, true, false><<<wb, 256, 0, stream>>>(offsets, csr, as2b, ad2b, ch2, b2,
                                                       o2, nullptr, nullptr, N);
    }
    // ---- layer 3: 64 -> 1 ----
    {
        l3_prep_k<<<wb, 256, 0, stream>>>(o2, W3, as3, ad3, h3, as3b, ad3b, N);
        agg3_k<<<wb, 256, 0, stream>>>(offsets, csr, as3b, ad3b, h3, b3, (float*)d_out, N);
    }
}

// Round 6
// 371.533 us; speedup vs baseline: 1.0481x; 1.0481x over previous
//
#include <hip/hip_runtime.h>
#include <hip/hip_bf16.h>
#include <hip/hip_fp16.h>
#include <math.h>

#define NEG_SLOPE 0.2f

typedef __attribute__((ext_vector_type(8))) short bf16x8_t;
typedef __attribute__((ext_vector_type(4))) float f32x4_t;

struct __align__(8) half4_t { __half2 a, b; };

// ---------------------------------------------------------------------------
// CSR build: histogram -> block scan -> scatter fill
// ---------------------------------------------------------------------------
__global__ void hist_k(const int* __restrict__ ei, int E, int n, int* __restrict__ deg) {
    int e = blockIdx.x * 256 + threadIdx.x;
    int ET = E + n;
    if (e >= ET) return;
    int d = (e < E) ? ei[E + e] : (e - E);
    atomicAdd(&deg[d], 1);
}

__global__ void scan1_k(const int* __restrict__ deg, int* __restrict__ incl,
                        int* __restrict__ bsums, int n) {
    __shared__ int s[256];
    int tid = threadIdx.x;
    int i = blockIdx.x * 256 + tid;
    int v = (i < n) ? deg[i] : 0;
    s[tid] = v;
    __syncthreads();
    for (int off = 1; off < 256; off <<= 1) {
        int t = (tid >= off) ? s[tid - off] : 0;
        __syncthreads();
        s[tid] += t;
        __syncthreads();
    }
    if (i < n) incl[i] = s[tid];
    if (tid == 255) bsums[blockIdx.x] = s[255];
}

__global__ void scan2_k(int* __restrict__ bsums, int nch) {
    __shared__ int s[256];
    int tid = threadIdx.x;
    int v = (tid < nch) ? bsums[tid] : 0;
    int orig = v;
    s[tid] = v;
    __syncthreads();
    for (int off = 1; off < 256; off <<= 1) {
        int t = (tid >= off) ? s[tid - off] : 0;
        __syncthreads();
        s[tid] += t;
        __syncthreads();
    }
    if (tid < nch) bsums[tid] = s[tid] - orig;  // exclusive
}

__global__ void scan3_k(int* __restrict__ offsets, int* __restrict__ cursor,
                        const int* __restrict__ bsums, int n, int total) {
    int i = blockIdx.x * 256 + threadIdx.x;
    if (i < n) {
        int excl = offsets[i] - cursor[i] + bsums[i >> 8];
        offsets[i] = excl;
        cursor[i]  = excl;
    }
    if (i == 0 && blockIdx.x == 0) offsets[n] = total;
}

__global__ void fill_k(const int* __restrict__ ei, int E, int n,
                       int* __restrict__ cursor, int* __restrict__ csr) {
    int e = blockIdx.x * 256 + threadIdx.x;
    int ET = E + n;
    if (e >= ET) return;
    int s, d;
    if (e < E) { s = ei[e]; d = ei[E + e]; }
    else       { s = e - E; d = e - E; }
    int pos = atomicAdd(&cursor[d], 1);
    csr[pos] = s;
}

// ---------------------------------------------------------------------------
// fp32 -> bf16 hi/lo split helpers
// ---------------------------------------------------------------------------
__device__ inline void bf16_split(float f, ushort& hi, ushort& lo) {
    unsigned int u = __float_as_uint(f);
    unsigned int r = u + 0x7FFFu + ((u >> 16) & 1u);
    hi = (ushort)(r >> 16);
    float back = __uint_as_float((unsigned int)hi << 16);
    float rem = f - back;
    unsigned int u2 = __float_as_uint(rem);
    unsigned int r2 = u2 + 0x7FFFu + ((u2 >> 16) & 1u);
    lo = (ushort)(r2 >> 16);
}

// A [M,K] fp32 -> Ah, Al [M,K] bf16 (row-major), 8 elems/thread
__global__ void splitA_k(const float* __restrict__ A, ushort* __restrict__ Ah,
                         ushort* __restrict__ Al, long total8) {
    long i = (long)blockIdx.x * 256 + threadIdx.x;
    if (i >= total8) return;
    const float* src = A + i * 8;
    float4 a = *(const float4*)src;
    float4 b = *(const float4*)(src + 4);
    float fv[8] = {a.x, a.y, a.z, a.w, b.x, b.y, b.z, b.w};
    ushort hv[8], lv[8];
#pragma unroll
    for (int q = 0; q < 8; q++) bf16_split(fv[q], hv[q], lv[q]);
    *(bf16x8_t*)(Ah + i * 8) = *(bf16x8_t*)hv;
    *(bf16x8_t*)(Al + i * 8) = *(bf16x8_t*)lv;
}

// W [K,N] fp32 -> WhT, WlT [N,K] bf16 (transposed)
__global__ void splitWT_k(const float* __restrict__ W, ushort* __restrict__ WhT,
                          ushort* __restrict__ WlT, int K, int N) {
    int idx = blockIdx.x * 256 + threadIdx.x;
    if (idx >= K * N) return;
    int k = idx / N, n = idx - k * N;
    ushort hi, lo;
    bf16_split(W[idx], hi, lo);
    WhT[(size_t)n * K + k] = hi;
    WlT[(size_t)n * K + k] = lo;
}

// ---------------------------------------------------------------------------
// split-bf16 MFMA GEMM core, presplit inputs, fused attention-prep epilogue.
// block tile 128x64, 4 waves (2Mx2N), wave tile 64x32, BK=32.
// ---------------------------------------------------------------------------
__device__ __forceinline__ void gemm_core(const ushort* __restrict__ Ah,
                                          const ushort* __restrict__ Al,
                                          const ushort* __restrict__ BhT,
                                          const ushort* __restrict__ BlT,
                                          __half* __restrict__ Ch,
                                          float* __restrict__ asb,
                                          float* __restrict__ adb,
                                          const float* __restrict__ a_src,
                                          const float* __restrict__ a_dst,
                                          int M, int K, int Nc) {
    __shared__ __align__(16) ushort sAh[128][40];
    __shared__ __align__(16) ushort sAl[128][40];
    __shared__ __align__(16) ushort sBh[64][40];
    __shared__ __align__(16) ushort sBl[64][40];

    const int tid  = threadIdx.x;
    const int lane = tid & 63;
    const int wv   = tid >> 6;
    const int wm   = wv & 1, wn = wv >> 1;
    const int m0   = blockIdx.x << 7;
    const int n0   = blockIdx.y << 6;

    f32x4_t acc[4][2];
#pragma unroll
    for (int i = 0; i < 4; i++)
#pragma unroll
        for (int j = 0; j < 2; j++) acc[i][j] = (f32x4_t){0.f, 0.f, 0.f, 0.f};

    const int arow = tid >> 1;          // 0..127
    const int acb  = (tid & 1) << 4;    // 0 / 16
    const int brow = tid >> 2;          // 0..63
    const int bkb  = (tid & 3) << 3;    // 0,8,16,24

    const bf16x8_t zv = {};

    for (int k0 = 0; k0 < K; k0 += 32) {
        {
            const int gr = m0 + arow;
            bf16x8_t h0 = zv, h1 = zv, l0 = zv, l1 = zv;
            if (gr < M) {
                const ushort* ph = Ah + (size_t)gr * K + k0 + acb;
                const ushort* pl = Al + (size_t)gr * K + k0 + acb;
                h0 = *(const bf16x8_t*)ph;
                h1 = *(const bf16x8_t*)(ph + 8);
                l0 = *(const bf16x8_t*)pl;
                l1 = *(const bf16x8_t*)(pl + 8);
            }
            *(bf16x8_t*)&sAh[arow][acb]     = h0;
            *(bf16x8_t*)&sAh[arow][acb + 8] = h1;
            *(bf16x8_t*)&sAl[arow][acb]     = l0;
            *(bf16x8_t*)&sAl[arow][acb + 8] = l1;
        }
        {
            const ushort* ph = BhT + (size_t)(n0 + brow) * K + k0 + bkb;
            const ushort* pl = BlT + (size_t)(n0 + brow) * K + k0 + bkb;
            *(bf16x8_t*)&sBh[brow][bkb] = *(const bf16x8_t*)ph;
            *(bf16x8_t*)&sBl[brow][bkb] = *(const bf16x8_t*)pl;
        }
        __syncthreads();
        bf16x8_t ah[4], al[4], bh[2], bl[2];
        const int rbase = (wm << 6) + (lane & 15);
        const int slot  = (lane >> 4) << 3;
#pragma unroll
        for (int mi = 0; mi < 4; mi++) {
            ah[mi] = *(const bf16x8_t*)&sAh[rbase + (mi << 4)][slot];
            al[mi] = *(const bf16x8_t*)&sAl[rbase + (mi << 4)][slot];
        }
        const int cbase = (wn << 5) + (lane & 15);
#pragma unroll
        for (int ni = 0; ni < 2; ni++) {
            bh[ni] = *(const bf16x8_t*)&sBh[cbase + (ni << 4)][slot];
            bl[ni] = *(const bf16x8_t*)&sBl[cbase + (ni << 4)][slot];
        }
#pragma unroll
        for (int mi = 0; mi < 4; mi++)
#pragma unroll
            for (int ni = 0; ni < 2; ni++) {
                acc[mi][ni] = __builtin_amdgcn_mfma_f32_16x16x32_bf16(ah[mi], bh[ni], acc[mi][ni], 0, 0, 0);
                acc[mi][ni] = __builtin_amdgcn_mfma_f32_16x16x32_bf16(ah[mi], bl[ni], acc[mi][ni], 0, 0, 0);
                acc[mi][ni] = __builtin_amdgcn_mfma_f32_16x16x32_bf16(al[mi], bh[ni], acc[mi][ni], 0, 0, 0);
            }
        __syncthreads();
    }

    // epilogue: C/D layout col=lane&15, row=(lane>>4)*4+reg
    const int col0 = n0 + (wn << 5) + (lane & 15);
    const float asv0 = a_src[col0],      adv0 = a_dst[col0];
    const float asv1 = a_src[col0 + 16], adv1 = a_dst[col0 + 16];

#pragma unroll
    for (int mi = 0; mi < 4; mi++) {
        const int row0 = m0 + (wm << 6) + (mi << 4) + ((lane >> 4) << 2);
#pragma unroll
        for (int ni = 0; ni < 2; ni++) {
            const int col = col0 + (ni << 4);
#pragma unroll
            for (int r = 0; r < 4; r++)
                if (row0 + r < M)
                    Ch[(size_t)(row0 + r) * Nc + col] = __float2half(acc[mi][ni][r]);
        }
        float ss[4], sd[4];
#pragma unroll
        for (int r = 0; r < 4; r++) {
            ss[r] = acc[mi][0][r] * asv0 + acc[mi][1][r] * asv1;
            sd[r] = acc[mi][0][r] * adv0 + acc[mi][1][r] * adv1;
        }
#pragma unroll
        for (int off = 1; off < 16; off <<= 1) {
#pragma unroll
            for (int r = 0; r < 4; r++) {
                ss[r] += __shfl_xor(ss[r], off);
                sd[r] += __shfl_xor(sd[r], off);
            }
        }
        if ((lane & 15) == 0) {
#pragma unroll
            for (int r = 0; r < 4; r++)
                if (row0 + r < M) {
                    atomicAdd(&asb[row0 + r], ss[r]);
                    atomicAdd(&adb[row0 + r], sd[r]);
                }
        }
    }
}

__global__ __launch_bounds__(256) void gemm1_k(const ushort* Ah, const ushort* Al,
                                               const ushort* BhT, const ushort* BlT,
                                               __half* Ch, float* asb, float* adb,
                                               const float* a_src, const float* a_dst,
                                               int M, int K, int Nc) {
    gemm_core(Ah, Al, BhT, BlT, Ch, asb, adb, a_src, a_dst, M, K, Nc);
}
__global__ __launch_bounds__(256) void gemm2_k(const ushort* Ah, const ushort* Al,
                                               const ushort* BhT, const ushort* BlT,
                                               __half* Ch, float* asb, float* adb,
                                               const float* a_src, const float* a_dst,
                                               int M, int K, int Nc) {
    gemm_core(Ah, Al, BhT, BlT, Ch, asb, adb, a_src, a_dst, M, K, Nc);
}

// ---------------------------------------------------------------------------
// fused per-node softmax + aggregation (wave per node), fp16 h gather.
// No max-subtraction: logits ~N(0,2); clamp +-60 as insurance, softmax ratio
// is unchanged. Two passes: (weights+sum) then (gather).
// SPLIT_OUT: write bf16 hi/lo (next GEMM's A). L3F: fuse 64->1 matmul +
// layer-3 logit pieces into the epilogue.
// ---------------------------------------------------------------------------
#define DEG_CAP 128

template <int D, bool DO_ELU, bool SPLIT_OUT, bool L3F>
__device__ __forceinline__ void agg_core(const int* __restrict__ offs,
                                         const int* __restrict__ csr,
                                         const float* __restrict__ asb,
                                         const float* __restrict__ adb,
                                         const __half* __restrict__ h,
                                         const float* __restrict__ bias,
                                         float* __restrict__ out,
                                         ushort* __restrict__ oh,
                                         ushort* __restrict__ ol,
                                         const float* __restrict__ W3,
                                         const float* __restrict__ as3,
                                         const float* __restrict__ ad3,
                                         float* __restrict__ h3o,
                                         float* __restrict__ as3b,
                                         float* __restrict__ ad3b, int n) {
    __shared__ float wsh[4][DEG_CAP];
    __shared__ int   osh[4][DEG_CAP];   // byte offsets j*D*2
    const int wv   = threadIdx.x >> 6;
    const int lane = threadIdx.x & 63;
    const int wid  = (blockIdx.x << 2) + wv;
    const bool active = wid < n;

    int beg = 0, deg = 0;
    float adi = 0.f;
    if (active) {
        beg = offs[wid];
        deg = offs[wid + 1] - beg;
        adi = adb[wid];
    }
    const int degc = deg < DEG_CAP ? deg : DEG_CAP;

    float inv = 0.f;
    if (active) {
        float ssum = 0.f;
        for (int e = lane; e < degc; e += 64) {
            int j = csr[beg + e];
            float v = asb[j] + adi;
            v = v > 0.f ? v : NEG_SLOPE * v;
            v = fminf(fmaxf(v, -60.f), 60.f);
            float w = __expf(v);
            osh[wv][e] = j * (int)(D * sizeof(__half));
            wsh[wv][e] = w;
            ssum += w;
        }
        for (int e = DEG_CAP + lane; e < deg; e += 64) {
            float v = asb[csr[beg + e]] + adi;
            v = v > 0.f ? v : NEG_SLOPE * v;
            v = fminf(fmaxf(v, -60.f), 60.f);
            ssum += __expf(v);
        }
#pragma unroll
        for (int o = 32; o; o >>= 1) ssum += __shfl_xor(ssum, o);
        inv = 1.f / ssum;
    }

    __syncthreads();

    if (!active) return;

    constexpr int U = D / 64;  // 4 (D=256) or 1 (D=64)
    float a0[U] = {}, a1[U] = {}, a2[U] = {}, a3[U] = {};
    const char* hb = (const char*)h + (U == 4 ? (lane << 3) : (lane << 1));

    int e = 0;
    for (; e + 4 <= degc; e += 4) {
        int o0 = osh[wv][e], o1 = osh[wv][e + 1], o2 = osh[wv][e + 2], o3 = osh[wv][e + 3];
        float w0 = wsh[wv][e], w1 = wsh[wv][e + 1], w2 = wsh[wv][e + 2], w3 = wsh[wv][e + 3];
        if constexpr (U == 4) {
            const half4_t h0 = *(const half4_t*)(hb + o0);
            const half4_t h1 = *(const half4_t*)(hb + o1);
            const half4_t h2 = *(const half4_t*)(hb + o2);
            const half4_t h3 = *(const half4_t*)(hb + o3);
            float2 f0a = __half22float2(h0.a), f0b = __half22float2(h0.b);
            float2 f1a = __half22float2(h1.a), f1b = __half22float2(h1.b);
            float2 f2a = __half22float2(h2.a), f2b = __half22float2(h2.b);
            float2 f3a = __half22float2(h3.a), f3b = __half22float2(h3.b);
            a0[0] = fmaf(w0, f0a.x, a0[0]); a0[1] = fmaf(w0, f0a.y, a0[1]);
            a0[2] = fmaf(w0, f0b.x, a0[2]); a0[3] = fmaf(w0, f0b.y, a0[3]);
            a1[0] = fmaf(w1, f1a.x, a1[0]); a1[1] = fmaf(w1, f1a.y, a1[1]);
            a1[2] = fmaf(w1, f1b.x, a1[2]); a1[3] = fmaf(w1, f1b.y, a1[3]);
            a2[0] = fmaf(w2, f2a.x, a2[0]); a2[1] = fmaf(w2, f2a.y, a2[1]);
            a2[2] = fmaf(w2, f2b.x, a2[2]); a2[3] = fmaf(w2, f2b.y, a2[3]);
            a3[0] = fmaf(w3, f3a.x, a3[0]); a3[1] = fmaf(w3, f3a.y, a3[1]);
            a3[2] = fmaf(w3, f3b.x, a3[2]); a3[3] = fmaf(w3, f3b.y, a3[3]);
        } else {
            a0[0] = fmaf(w0, __half2float(*(const __half*)(hb + o0)), a0[0]);
            a1[0] = fmaf(w1, __half2float(*(const __half*)(hb + o1)), a1[0]);
            a2[0] = fmaf(w2, __half2float(*(const __half*)(hb + o2)), a2[0]);
            a3[0] = fmaf(w3, __half2float(*(const __half*)(hb + o3)), a3[0]);
        }
    }
    for (; e < degc; ++e) {
        int o0 = osh[wv][e];
        float ww = wsh[wv][e];
        if constexpr (U == 4) {
            const half4_t hv = *(const half4_t*)(hb + o0);
            float2 fa = __half22float2(hv.a), fb = __half22float2(hv.b);
            a0[0] = fmaf(ww, fa.x, a0[0]); a0[1] = fmaf(ww, fa.y, a0[1]);
            a0[2] = fmaf(ww, fb.x, a0[2]); a0[3] = fmaf(ww, fb.y, a0[3]);
        } else {
            a0[0] = fmaf(ww, __half2float(*(const __half*)(hb + o0)), a0[0]);
        }
    }
    for (int eo = DEG_CAP; eo < deg; ++eo) {
        int j = csr[beg + eo];
        float v = asb[j] + adi;
        v = v > 0.f ? v : NEG_SLOPE * v;
        v = fminf(fmaxf(v, -60.f), 60.f);
        float ww = __expf(v);
        int o0 = j * (int)(D * sizeof(__half));
        if constexpr (U == 4) {
            const half4_t hv = *(const half4_t*)(hb + o0);
            float2 fa = __half22float2(hv.a), fb = __half22float2(hv.b);
            a0[0] = fmaf(ww, fa.x, a0[0]); a0[1] = fmaf(ww, fa.y, a0[1]);
            a0[2] = fmaf(ww, fb.x, a0[2]); a0[3] = fmaf(ww, fb.y, a0[3]);
        } else {
            a0[0] = fmaf(ww, __half2float(*(const __half*)(hb + o0)), a0[0]);
        }
    }

    if constexpr (U == 4) {
        float t[4];
#pragma unroll
        for (int u = 0; u < 4; u++) {
            float v = (a0[u] + a1[u] + a2[u] + a3[u]) * inv + bias[(lane << 2) + u];
            if (DO_ELU) v = v > 0.f ? v : expm1f(v);
            t[u] = v;
        }
        if constexpr (SPLIT_OUT) {
            ushort hv[4], lv[4];
#pragma unroll
            for (int u = 0; u < 4; u++) bf16_split(t[u], hv[u], lv[u]);
            *(ushort4*)(oh + (size_t)wid * D + (lane << 2)) = make_ushort4(hv[0], hv[1], hv[2], hv[3]);
            *(ushort4*)(ol + (size_t)wid * D + (lane << 2)) = make_ushort4(lv[0], lv[1], lv[2], lv[3]);
        } else {
            *(float4*)(out + (size_t)wid * D + (lane << 2)) = make_float4(t[0], t[1], t[2], t[3]);
        }
    } else {
        float t = (a0[0] + a1[0] + a2[0] + a3[0]) * inv + bias[lane];
        if (DO_ELU) t = t > 0.f ? t : expm1f(t);
        if constexpr (L3F) {
            float c = t * W3[lane];
#pragma unroll
            for (int o = 32; o; o >>= 1) c += __shfl_xor(c, o);
            if (lane == 0) {
                h3o[wid]  = c;
                as3b[wid] = c * as3[0];
                ad3b[wid] = c * ad3[0];
            }
        } else {
            out[(size_t)wid * D + lane] = t;
        }
    }
}

__global__ __launch_bounds__(256) void agg1_k(const int* offs, const int* csr,
                                              const float* asb, const float* adb,
                                              const __half* h, const float* bias,
                                              ushort* oh, ushort* ol, int n) {
    agg_core<256, true, true, false>(offs, csr, asb, adb, h, bias,
                                     nullptr, oh, ol,
                                     nullptr, nullptr, nullptr,
                                     nullptr, nullptr, nullptr, n);
}

__global__ __launch_bounds__(256) void agg2_k(const int* offs, const int* csr,
                                              const float* asb, const float* adb,
                                              const __half* h, const float* bias,
                                              const float* W3, const float* as3,
                                              const float* ad3, float* h3o,
                                              float* as3b, float* ad3b, int n) {
    agg_core<64, true, false, true>(offs, csr, asb, adb, h, bias,
                                    nullptr, nullptr, nullptr,
                                    W3, as3, ad3, h3o, as3b, ad3b, n);
}

// ---------------------------------------------------------------------------
// layer 3 aggregation: single pass (no max, clamped exp)
// ---------------------------------------------------------------------------
__global__ void agg3_k(const int* __restrict__ offs, const int* __restrict__ csr,
                       const float* __restrict__ asb, const float* __restrict__ adb,
                       const float* __restrict__ h3, const float* __restrict__ b3,
                       float* __restrict__ out, int n) {
    int wid = (blockIdx.x << 2) + (threadIdx.x >> 6);
    int lane = threadIdx.x & 63;
    if (wid >= n) return;
    int beg = offs[wid], end = offs[wid + 1];
    float adi = adb[wid];

    float ssum = 0.f, acc = 0.f;
    for (int e = beg + lane; e < end; e += 64) {
        int j = csr[e];
        float v = asb[j] + adi;
        v = v > 0.f ? v : NEG_SLOPE * v;
        v = fminf(fmaxf(v, -60.f), 60.f);
        float w = __expf(v);
        ssum += w;
        acc = fmaf(w, h3[j], acc);
    }
#pragma unroll
    for (int o = 32; o; o >>= 1) {
        ssum += __shfl_xor(ssum, o);
        acc  += __shfl_xor(acc, o);
    }
    if (lane == 0) out[wid] = acc / ssum + b3[0];
}

// ---------------------------------------------------------------------------
extern "C" void kernel_launch(void* const* d_in, const int* in_sizes, int n_in,
                              void* d_out, int out_size, void* d_ws, size_t ws_size,
                              hipStream_t stream) {
    const float* x   = (const float*)d_in[0];
    const int*   ei  = (const int*)d_in[1];
    const float* W1  = (const float*)d_in[2];
    const float* as1 = (const float*)d_in[3];
    const float* ad1 = (const float*)d_in[4];
    const float* b1  = (const float*)d_in[5];
    const float* W2  = (const float*)d_in[6];
    const float* as2 = (const float*)d_in[7];
    const float* ad2 = (const float*)d_in[8];
    const float* b2  = (const float*)d_in[9];
    const float* W3  = (const float*)d_in[10];
    const float* as3 = (const float*)d_in[11];
    const float* ad3 = (const float*)d_in[12];
    const float* b3  = (const float*)d_in[13];

    const int d1 = in_sizes[3];                    // 256
    const int C  = in_sizes[2] / d1;               // 128
    const int N  = in_sizes[0] / C;                // 50000
    const int E  = in_sizes[1] / 2;                // 800000
    const int d2 = in_sizes[7];                    // 64
    const int ET = E + N;                          // 850000

    char* p = (char*)d_ws;
    auto alloc = [&](size_t bytes) -> void* {
        void* q = (void*)p;
        p += (bytes + 255) & ~(size_t)255;
        return q;
    };
    int*    offsets = (int*)alloc(sizeof(int) * (size_t)(N + 1));
    int*    cursor  = (int*)alloc(sizeof(int) * (size_t)N);
    int*    bsums   = (int*)alloc(sizeof(int) * 256);
    int*    csr     = (int*)alloc(sizeof(int) * (size_t)ET);
    float*  alpha   = (float*)alloc(sizeof(float) * (size_t)4 * N);  // as1b,ad1b,as2b,ad2b
    float*  as1b = alpha, *ad1b = alpha + N, *as2b = alpha + 2 * N, *ad2b = alpha + 3 * N;
    ushort* xh      = (ushort*)alloc(sizeof(ushort) * (size_t)N * C);
    ushort* xl      = (ushort*)alloc(sizeof(ushort) * (size_t)N * C);
    ushort* w1h     = (ushort*)alloc(sizeof(ushort) * (size_t)C * d1);
    ushort* w1l     = (ushort*)alloc(sizeof(ushort) * (size_t)C * d1);
    ushort* w2h     = (ushort*)alloc(sizeof(ushort) * (size_t)d1 * d2);
    ushort* w2l     = (ushort*)alloc(sizeof(ushort) * (size_t)d1 * d2);
    __half* ch1     = (__half*)alloc(sizeof(__half) * (size_t)N * d1);
    ushort* o1h     = (ushort*)alloc(sizeof(ushort) * (size_t)N * d1);
    ushort* o1l     = (ushort*)alloc(sizeof(ushort) * (size_t)N * d1);
    __half* ch2     = (__half*)alloc(sizeof(__half) * (size_t)N * d2);
    float*  h3      = (float*)alloc(sizeof(float) * (size_t)N);
    float*  as3b    = (float*)alloc(sizeof(float) * (size_t)N);
    float*  ad3b    = (float*)alloc(sizeof(float) * (size_t)N);

    const int eb  = (ET + 255) / 256;
    const int nch = (N + 255) / 256;
    const int wb  = (N + 3) / 4;

    hipMemsetAsync(cursor, 0, sizeof(int) * (size_t)N, stream);
    hipMemsetAsync(alpha, 0, sizeof(float) * (size_t)4 * N, stream);

    // ---- CSR build ----
    hist_k<<<eb, 256, 0, stream>>>(ei, E, N, cursor);
    scan1_k<<<nch, 256, 0, stream>>>(cursor, offsets, bsums, N);
    scan2_k<<<1, 256, 0, stream>>>(bsums, nch);
    scan3_k<<<nch, 256, 0, stream>>>(offsets, cursor, bsums, N, ET);
    fill_k<<<eb, 256, 0, stream>>>(ei, E, N, cursor, csr);

    // ---- presplit inputs & weights ----
    {
        long t8 = (long)N * C / 8;
        splitA_k<<<(int)((t8 + 255) / 256), 256, 0, stream>>>(x, xh, xl, t8);
        splitWT_k<<<(C * d1 + 255) / 256, 256, 0, stream>>>(W1, w1h, w1l, C, d1);
        splitWT_k<<<(d1 * d2 + 255) / 256, 256, 0, stream>>>(W2, w2h, w2l, d1, d2);
    }

    // ---- layer 1: 128 -> 256, ELU ----
    {
        dim3 g((N + 127) / 128, d1 / 64);
        gemm1_k<<<g, 256, 0, stream>>>(xh, xl, w1h, w1l, ch1, as1b, ad1b, as1, ad1, N, C, d1);
        agg1_k<<<wb, 256, 0, stream>>>(offsets, csr, as1b, ad1b, ch1, b1, o1h, o1l, N);
    }
    // ---- layer 2: 256 -> 64, ELU, fused layer-3 prep ----
    {
        dim3 g((N + 127) / 128, d2 / 64);
        gemm2_k<<<g, 256, 0, stream>>>(o1h, o1l, w2h, w2l, ch2, as2b, ad2b, as2, ad2, N, d1, d2);
        agg2_k<<<wb, 256, 0, stream>>>(offsets, csr, as2b, ad2b, ch2, b2,
                                       W3, as3, ad3, h3, as3b, ad3b, N);
    }
    // ---- layer 3: aggregation ----
    agg3_k<<<wb, 256, 0, stream>>>(offsets, csr, as3b, ad3b, h3, b3, (float*)d_out, N);
}

// Round 7
// 346.716 us; speedup vs baseline: 1.1231x; 1.0716x over previous
//
#include <hip/hip_runtime.h>
#include <hip/hip_bf16.h>
#include <hip/hip_fp16.h>
#include <math.h>

#define NEG_SLOPE 0.2f

typedef __attribute__((ext_vector_type(8))) short      s16x8_t;
typedef __attribute__((ext_vector_type(8))) _Float16   f16x8_t;
typedef __attribute__((ext_vector_type(4))) float      f32x4_t;

struct __align__(8) half4_t { __half2 a, b; };

// ---------------------------------------------------------------------------
// CSR build: histogram -> block scan -> scatter fill
// ---------------------------------------------------------------------------
__global__ void hist_k(const int* __restrict__ ei, int E, int n, int* __restrict__ deg) {
    int e = blockIdx.x * 256 + threadIdx.x;
    int ET = E + n;
    if (e >= ET) return;
    int d = (e < E) ? ei[E + e] : (e - E);
    atomicAdd(&deg[d], 1);
}

__global__ void scan1_k(const int* __restrict__ deg, int* __restrict__ incl,
                        int* __restrict__ bsums, int n) {
    __shared__ int s[256];
    int tid = threadIdx.x;
    int i = blockIdx.x * 256 + tid;
    int v = (i < n) ? deg[i] : 0;
    s[tid] = v;
    __syncthreads();
    for (int off = 1; off < 256; off <<= 1) {
        int t = (tid >= off) ? s[tid - off] : 0;
        __syncthreads();
        s[tid] += t;
        __syncthreads();
    }
    if (i < n) incl[i] = s[tid];
    if (tid == 255) bsums[blockIdx.x] = s[255];
}

__global__ void scan2_k(int* __restrict__ bsums, int nch) {
    __shared__ int s[256];
    int tid = threadIdx.x;
    int v = (tid < nch) ? bsums[tid] : 0;
    int orig = v;
    s[tid] = v;
    __syncthreads();
    for (int off = 1; off < 256; off <<= 1) {
        int t = (tid >= off) ? s[tid - off] : 0;
        __syncthreads();
        s[tid] += t;
        __syncthreads();
    }
    if (tid < nch) bsums[tid] = s[tid] - orig;  // exclusive
}

__global__ void scan3_k(int* __restrict__ offsets, int* __restrict__ cursor,
                        const int* __restrict__ bsums, int n, int total) {
    int i = blockIdx.x * 256 + threadIdx.x;
    if (i < n) {
        int excl = offsets[i] - cursor[i] + bsums[i >> 8];
        offsets[i] = excl;
        cursor[i]  = excl;
    }
    if (i == 0 && blockIdx.x == 0) offsets[n] = total;
}

__global__ void fill_k(const int* __restrict__ ei, int E, int n,
                       int* __restrict__ cursor, int* __restrict__ csr) {
    int e = blockIdx.x * 256 + threadIdx.x;
    int ET = E + n;
    if (e >= ET) return;
    int s, d;
    if (e < E) { s = ei[e]; d = ei[E + e]; }
    else       { s = e - E; d = e - E; }
    int pos = atomicAdd(&cursor[d], 1);
    csr[pos] = s;
}

// ---------------------------------------------------------------------------
// fp32 -> fp16 converts
// ---------------------------------------------------------------------------
__global__ void cvtA_k(const float* __restrict__ A, __half* __restrict__ Af,
                       long total8) {
    long i = (long)blockIdx.x * 256 + threadIdx.x;
    if (i >= total8) return;
    const float* src = A + i * 8;
    float4 a = *(const float4*)src;
    float4 b = *(const float4*)(src + 4);
    half4_t o0, o1;
    o0.a = __floats2half2_rn(a.x, a.y);
    o0.b = __floats2half2_rn(a.z, a.w);
    o1.a = __floats2half2_rn(b.x, b.y);
    o1.b = __floats2half2_rn(b.z, b.w);
    *(half4_t*)(Af + i * 8)     = o0;
    *(half4_t*)(Af + i * 8 + 4) = o1;
}

// W [K,N] fp32 -> WT [N,K] fp16 (transposed)
__global__ void cvtWT_k(const float* __restrict__ W, __half* __restrict__ WT,
                        int K, int N) {
    int idx = blockIdx.x * 256 + threadIdx.x;
    if (idx >= K * N) return;
    int k = idx / N, n = idx - k * N;
    WT[(size_t)n * K + k] = __float2half(W[idx]);
}

// ---------------------------------------------------------------------------
// fp16 MFMA GEMM (1-term), fused attention-prep epilogue.
// A [M,K] fp16 row-major. BT [Nc,K] fp16 (transposed). C accum fp32 in MFMA.
// Writes Ch fp16 [M,Nc]; atomic-accumulates asb/adb = h·a_src / h·a_dst.
// block tile 128x64, 4 waves (2Mx2N), wave tile 64x32, BK=32.
// ---------------------------------------------------------------------------
__device__ __forceinline__ void gemm_core(const ushort* __restrict__ A,
                                          const ushort* __restrict__ BT,
                                          __half* __restrict__ Ch,
                                          float* __restrict__ asb,
                                          float* __restrict__ adb,
                                          const float* __restrict__ a_src,
                                          const float* __restrict__ a_dst,
                                          int M, int K, int Nc) {
    __shared__ __align__(16) ushort sA[128][40];
    __shared__ __align__(16) ushort sB[64][40];

    const int tid  = threadIdx.x;
    const int lane = tid & 63;
    const int wv   = tid >> 6;
    const int wm   = wv & 1, wn = wv >> 1;
    const int m0   = blockIdx.x << 7;
    const int n0   = blockIdx.y << 6;

    f32x4_t acc[4][2];
#pragma unroll
    for (int i = 0; i < 4; i++)
#pragma unroll
        for (int j = 0; j < 2; j++) acc[i][j] = (f32x4_t){0.f, 0.f, 0.f, 0.f};

    const int arow = tid >> 1;          // 0..127
    const int acb  = (tid & 1) << 4;    // 0 / 16
    const int brow = tid >> 2;          // 0..63
    const int bkb  = (tid & 3) << 3;    // 0,8,16,24

    const s16x8_t zv = {};

    for (int k0 = 0; k0 < K; k0 += 32) {
        {
            const int gr = m0 + arow;
            s16x8_t v0 = zv, v1 = zv;
            if (gr < M) {
                const ushort* pa = A + (size_t)gr * K + k0 + acb;
                v0 = *(const s16x8_t*)pa;
                v1 = *(const s16x8_t*)(pa + 8);
            }
            *(s16x8_t*)&sA[arow][acb]     = v0;
            *(s16x8_t*)&sA[arow][acb + 8] = v1;
        }
        {
            const ushort* pb = BT + (size_t)(n0 + brow) * K + k0 + bkb;
            *(s16x8_t*)&sB[brow][bkb] = *(const s16x8_t*)pb;
        }
        __syncthreads();
        f16x8_t af[4], bf[2];
        const int rbase = (wm << 6) + (lane & 15);
        const int slot  = (lane >> 4) << 3;
#pragma unroll
        for (int mi = 0; mi < 4; mi++)
            af[mi] = *(const f16x8_t*)&sA[rbase + (mi << 4)][slot];
        const int cbase = (wn << 5) + (lane & 15);
#pragma unroll
        for (int ni = 0; ni < 2; ni++)
            bf[ni] = *(const f16x8_t*)&sB[cbase + (ni << 4)][slot];
#pragma unroll
        for (int mi = 0; mi < 4; mi++)
#pragma unroll
            for (int ni = 0; ni < 2; ni++)
                acc[mi][ni] = __builtin_amdgcn_mfma_f32_16x16x32_f16(af[mi], bf[ni], acc[mi][ni], 0, 0, 0);
        __syncthreads();
    }

    // epilogue: C/D layout col=lane&15, row=(lane>>4)*4+reg
    const int col0 = n0 + (wn << 5) + (lane & 15);
    const float asv0 = a_src[col0],      adv0 = a_dst[col0];
    const float asv1 = a_src[col0 + 16], adv1 = a_dst[col0 + 16];

#pragma unroll
    for (int mi = 0; mi < 4; mi++) {
        const int row0 = m0 + (wm << 6) + (mi << 4) + ((lane >> 4) << 2);
#pragma unroll
        for (int ni = 0; ni < 2; ni++) {
            const int col = col0 + (ni << 4);
#pragma unroll
            for (int r = 0; r < 4; r++)
                if (row0 + r < M)
                    Ch[(size_t)(row0 + r) * Nc + col] = __float2half(acc[mi][ni][r]);
        }
        float ss[4], sd[4];
#pragma unroll
        for (int r = 0; r < 4; r++) {
            ss[r] = acc[mi][0][r] * asv0 + acc[mi][1][r] * asv1;
            sd[r] = acc[mi][0][r] * adv0 + acc[mi][1][r] * adv1;
        }
#pragma unroll
        for (int off = 1; off < 16; off <<= 1) {
#pragma unroll
            for (int r = 0; r < 4; r++) {
                ss[r] += __shfl_xor(ss[r], off);
                sd[r] += __shfl_xor(sd[r], off);
            }
        }
        if ((lane & 15) == 0) {
#pragma unroll
            for (int r = 0; r < 4; r++)
                if (row0 + r < M) {
                    atomicAdd(&asb[row0 + r], ss[r]);
                    atomicAdd(&adb[row0 + r], sd[r]);
                }
        }
    }
}

__global__ __launch_bounds__(256) void gemm1_k(const ushort* A, const ushort* BT,
                                               __half* Ch, float* asb, float* adb,
                                               const float* a_src, const float* a_dst,
                                               int M, int K, int Nc) {
    gemm_core(A, BT, Ch, asb, adb, a_src, a_dst, M, K, Nc);
}
__global__ __launch_bounds__(256) void gemm2_k(const ushort* A, const ushort* BT,
                                               __half* Ch, float* asb, float* adb,
                                               const float* a_src, const float* a_dst,
                                               int M, int K, int Nc) {
    gemm_core(A, BT, Ch, asb, adb, a_src, a_dst, M, K, Nc);
}

// ---------------------------------------------------------------------------
// fused per-node softmax + aggregation (wave per node), fp16 h gather.
// No max-subtraction (clamp +-60). Two passes: (weights+sum), (gather).
// OUT16: write fp16 (next GEMM's A = gather copy). L3F: fuse 64->1 matmul +
// layer-3 logit pieces.
// ---------------------------------------------------------------------------
#define DEG_CAP 128

template <int D, bool DO_ELU, bool OUT16, bool L3F>
__device__ __forceinline__ void agg_core(const int* __restrict__ offs,
                                         const int* __restrict__ csr,
                                         const float* __restrict__ asb,
                                         const float* __restrict__ adb,
                                         const __half* __restrict__ h,
                                         const float* __restrict__ bias,
                                         float* __restrict__ out,
                                         __half* __restrict__ o16,
                                         const float* __restrict__ W3,
                                         const float* __restrict__ as3,
                                         const float* __restrict__ ad3,
                                         float* __restrict__ h3o,
                                         float* __restrict__ as3b,
                                         float* __restrict__ ad3b, int n) {
    __shared__ float wsh[4][DEG_CAP];
    __shared__ int   osh[4][DEG_CAP];   // byte offsets j*D*2
    const int wv   = threadIdx.x >> 6;
    const int lane = threadIdx.x & 63;
    const int wid  = (blockIdx.x << 2) + wv;
    const bool active = wid < n;

    int beg = 0, deg = 0;
    float adi = 0.f;
    if (active) {
        beg = offs[wid];
        deg = offs[wid + 1] - beg;
        adi = adb[wid];
    }
    const int degc = deg < DEG_CAP ? deg : DEG_CAP;

    float inv = 0.f;
    if (active) {
        float ssum = 0.f;
        for (int e = lane; e < degc; e += 64) {
            int j = csr[beg + e];
            float v = asb[j] + adi;
            v = v > 0.f ? v : NEG_SLOPE * v;
            v = fminf(fmaxf(v, -60.f), 60.f);
            float w = __expf(v);
            osh[wv][e] = j * (int)(D * sizeof(__half));
            wsh[wv][e] = w;
            ssum += w;
        }
        for (int e = DEG_CAP + lane; e < deg; e += 64) {
            float v = asb[csr[beg + e]] + adi;
            v = v > 0.f ? v : NEG_SLOPE * v;
            v = fminf(fmaxf(v, -60.f), 60.f);
            ssum += __expf(v);
        }
#pragma unroll
        for (int o = 32; o; o >>= 1) ssum += __shfl_xor(ssum, o);
        inv = 1.f / ssum;
    }

    __syncthreads();

    if (!active) return;

    constexpr int U = D / 64;  // 4 (D=256) or 1 (D=64)
    float a0[U] = {}, a1[U] = {}, a2[U] = {}, a3[U] = {};
    const char* hb = (const char*)h + (U == 4 ? (lane << 3) : (lane << 1));

    int e = 0;
    for (; e + 4 <= degc; e += 4) {
        int o0 = osh[wv][e], o1 = osh[wv][e + 1], o2 = osh[wv][e + 2], o3 = osh[wv][e + 3];
        float w0 = wsh[wv][e], w1 = wsh[wv][e + 1], w2 = wsh[wv][e + 2], w3 = wsh[wv][e + 3];
        if constexpr (U == 4) {
            const half4_t h0 = *(const half4_t*)(hb + o0);
            const half4_t h1 = *(const half4_t*)(hb + o1);
            const half4_t h2 = *(const half4_t*)(hb + o2);
            const half4_t h3 = *(const half4_t*)(hb + o3);
            float2 f0a = __half22float2(h0.a), f0b = __half22float2(h0.b);
            float2 f1a = __half22float2(h1.a), f1b = __half22float2(h1.b);
            float2 f2a = __half22float2(h2.a), f2b = __half22float2(h2.b);
            float2 f3a = __half22float2(h3.a), f3b = __half22float2(h3.b);
            a0[0] = fmaf(w0, f0a.x, a0[0]); a0[1] = fmaf(w0, f0a.y, a0[1]);
            a0[2] = fmaf(w0, f0b.x, a0[2]); a0[3] = fmaf(w0, f0b.y, a0[3]);
            a1[0] = fmaf(w1, f1a.x, a1[0]); a1[1] = fmaf(w1, f1a.y, a1[1]);
            a1[2] = fmaf(w1, f1b.x, a1[2]); a1[3] = fmaf(w1, f1b.y, a1[3]);
            a2[0] = fmaf(w2, f2a.x, a2[0]); a2[1] = fmaf(w2, f2a.y, a2[1]);
            a2[2] = fmaf(w2, f2b.x, a2[2]); a2[3] = fmaf(w2, f2b.y, a2[3]);
            a3[0] = fmaf(w3, f3a.x, a3[0]); a3[1] = fmaf(w3, f3a.y, a3[1]);
            a3[2] = fmaf(w3, f3b.x, a3[2]); a3[3] = fmaf(w3, f3b.y, a3[3]);
        } else {
            a0[0] = fmaf(w0, __half2float(*(const __half*)(hb + o0)), a0[0]);
            a1[0] = fmaf(w1, __half2float(*(const __half*)(hb + o1)), a1[0]);
            a2[0] = fmaf(w2, __half2float(*(const __half*)(hb + o2)), a2[0]);
            a3[0] = fmaf(w3, __half2float(*(const __half*)(hb + o3)), a3[0]);
        }
    }
    for (; e < degc; ++e) {
        int o0 = osh[wv][e];
        float ww = wsh[wv][e];
        if constexpr (U == 4) {
            const half4_t hv = *(const half4_t*)(hb + o0);
            float2 fa = __half22float2(hv.a), fb = __half22float2(hv.b);
            a0[0] = fmaf(ww, fa.x, a0[0]); a0[1] = fmaf(ww, fa.y, a0[1]);
            a0[2] = fmaf(ww, fb.x, a0[2]); a0[3] = fmaf(ww, fb.y, a0[3]);
        } else {
            a0[0] = fmaf(ww, __half2float(*(const __half*)(hb + o0)), a0[0]);
        }
    }
    for (int eo = DEG_CAP; eo < deg; ++eo) {
        int j = csr[beg + eo];
        float v = asb[j] + adi;
        v = v > 0.f ? v : NEG_SLOPE * v;
        v = fminf(fmaxf(v, -60.f), 60.f);
        float ww = __expf(v);
        int o0 = j * (int)(D * sizeof(__half));
        if constexpr (U == 4) {
            const half4_t hv = *(const half4_t*)(hb + o0);
            float2 fa = __half22float2(hv.a), fb = __half22float2(hv.b);
            a0[0] = fmaf(ww, fa.x, a0[0]); a0[1] = fmaf(ww, fa.y, a0[1]);
            a0[2] = fmaf(ww, fb.x, a0[2]); a0[3] = fmaf(ww, fb.y, a0[3]);
        } else {
            a0[0] = fmaf(ww, __half2float(*(const __half*)(hb + o0)), a0[0]);
        }
    }

    if constexpr (U == 4) {
        float t[4];
#pragma unroll
        for (int u = 0; u < 4; u++) {
            float v = (a0[u] + a1[u] + a2[u] + a3[u]) * inv + bias[(lane << 2) + u];
            if (DO_ELU) v = v > 0.f ? v : expm1f(v);
            t[u] = v;
        }
        if constexpr (OUT16) {
            half4_t o;
            o.a = __floats2half2_rn(t[0], t[1]);
            o.b = __floats2half2_rn(t[2], t[3]);
            *(half4_t*)(o16 + (size_t)wid * D + (lane << 2)) = o;
        } else {
            *(float4*)(out + (size_t)wid * D + (lane << 2)) = make_float4(t[0], t[1], t[2], t[3]);
        }
    } else {
        float t = (a0[0] + a1[0] + a2[0] + a3[0]) * inv + bias[lane];
        if (DO_ELU) t = t > 0.f ? t : expm1f(t);
        if constexpr (L3F) {
            float c = t * W3[lane];
#pragma unroll
            for (int o = 32; o; o >>= 1) c += __shfl_xor(c, o);
            if (lane == 0) {
                h3o[wid]  = c;
                as3b[wid] = c * as3[0];
                ad3b[wid] = c * ad3[0];
            }
        } else {
            out[(size_t)wid * D + lane] = t;
        }
    }
}

__global__ __launch_bounds__(256) void agg1_k(const int* offs, const int* csr,
                                              const float* asb, const float* adb,
                                              const __half* h, const float* bias,
                                              __half* o16, int n) {
    agg_core<256, true, true, false>(offs, csr, asb, adb, h, bias,
                                     nullptr, o16,
                                     nullptr, nullptr, nullptr,
                                     nullptr, nullptr, nullptr, n);
}

__global__ __launch_bounds__(256) void agg2_k(const int* offs, const int* csr,
                                              const float* asb, const float* adb,
                                              const __half* h, const float* bias,
                                              const float* W3, const float* as3,
                                              const float* ad3, float* h3o,
                                              float* as3b, float* ad3b, int n) {
    agg_core<64, true, false, true>(offs, csr, asb, adb, h, bias,
                                    nullptr, nullptr,
                                    W3, as3, ad3, h3o, as3b, ad3b, n);
}

// ---------------------------------------------------------------------------
// layer 3 aggregation: single pass (no max, clamped exp)
// ---------------------------------------------------------------------------
__global__ void agg3_k(const int* __restrict__ offs, const int* __restrict__ csr,
                       const float* __restrict__ asb, const float* __restrict__ adb,
                       const float* __restrict__ h3, const float* __restrict__ b3,
                       float* __restrict__ out, int n) {
    int wid = (blockIdx.x << 2) + (threadIdx.x >> 6);
    int lane = threadIdx.x & 63;
    if (wid >= n) return;
    int beg = offs[wid], end = offs[wid + 1];
    float adi = adb[wid];

    float ssum = 0.f, acc = 0.f;
    for (int e = beg + lane; e < end; e += 64) {
        int j = csr[e];
        float v = asb[j] + adi;
        v = v > 0.f ? v : NEG_SLOPE * v;
        v = fminf(fmaxf(v, -60.f), 60.f);
        float w = __expf(v);
        ssum += w;
        acc = fmaf(w, h3[j], acc);
    }
#pragma unroll
    for (int o = 32; o; o >>= 1) {
        ssum += __shfl_xor(ssum, o);
        acc  += __shfl_xor(acc, o);
    }
    if (lane == 0) out[wid] = acc / ssum + b3[0];
}

// ---------------------------------------------------------------------------
extern "C" void kernel_launch(void* const* d_in, const int* in_sizes, int n_in,
                              void* d_out, int out_size, void* d_ws, size_t ws_size,
                              hipStream_t stream) {
    const float* x   = (const float*)d_in[0];
    const int*   ei  = (const int*)d_in[1];
    const float* W1  = (const float*)d_in[2];
    const float* as1 = (const float*)d_in[3];
    const float* ad1 = (const float*)d_in[4];
    const float* b1  = (const float*)d_in[5];
    const float* W2  = (const float*)d_in[6];
    const float* as2 = (const float*)d_in[7];
    const float* ad2 = (const float*)d_in[8];
    const float* b2  = (const float*)d_in[9];
    const float* W3  = (const float*)d_in[10];
    const float* as3 = (const float*)d_in[11];
    const float* ad3 = (const float*)d_in[12];
    const float* b3  = (const float*)d_in[13];

    const int d1 = in_sizes[3];                    // 256
    const int C  = in_sizes[2] / d1;               // 128
    const int N  = in_sizes[0] / C;                // 50000
    const int E  = in_sizes[1] / 2;                // 800000
    const int d2 = in_sizes[7];                    // 64
    const int ET = E + N;                          // 850000

    char* p = (char*)d_ws;
    auto alloc = [&](size_t bytes) -> void* {
        void* q = (void*)p;
        p += (bytes + 255) & ~(size_t)255;
        return q;
    };
    int*    offsets = (int*)alloc(sizeof(int) * (size_t)(N + 1));
    int*    cursor  = (int*)alloc(sizeof(int) * (size_t)N);
    int*    bsums   = (int*)alloc(sizeof(int) * 256);
    int*    csr     = (int*)alloc(sizeof(int) * (size_t)ET);
    float*  alpha   = (float*)alloc(sizeof(float) * (size_t)4 * N);  // as1b,ad1b,as2b,ad2b
    float*  as1b = alpha, *ad1b = alpha + N, *as2b = alpha + 2 * N, *ad2b = alpha + 3 * N;
    __half* xf      = (__half*)alloc(sizeof(__half) * (size_t)N * C);
    __half* w1t     = (__half*)alloc(sizeof(__half) * (size_t)C * d1);
    __half* w2t     = (__half*)alloc(sizeof(__half) * (size_t)d1 * d2);
    __half* ch1     = (__half*)alloc(sizeof(__half) * (size_t)N * d1);
    __half* o1      = (__half*)alloc(sizeof(__half) * (size_t)N * d1);
    __half* ch2     = (__half*)alloc(sizeof(__half) * (size_t)N * d2);
    float*  h3      = (float*)alloc(sizeof(float) * (size_t)N);
    float*  as3b    = (float*)alloc(sizeof(float) * (size_t)N);
    float*  ad3b    = (float*)alloc(sizeof(float) * (size_t)N);

    const int eb  = (ET + 255) / 256;
    const int nch = (N + 255) / 256;
    const int wb  = (N + 3) / 4;

    hipMemsetAsync(cursor, 0, sizeof(int) * (size_t)N, stream);
    hipMemsetAsync(alpha, 0, sizeof(float) * (size_t)4 * N, stream);

    // ---- CSR build ----
    hist_k<<<eb, 256, 0, stream>>>(ei, E, N, cursor);
    scan1_k<<<nch, 256, 0, stream>>>(cursor, offsets, bsums, N);
    scan2_k<<<1, 256, 0, stream>>>(bsums, nch);
    scan3_k<<<nch, 256, 0, stream>>>(offsets, cursor, bsums, N, ET);
    fill_k<<<eb, 256, 0, stream>>>(ei, E, N, cursor, csr);

    // ---- converts ----
    {
        long t8 = (long)N * C / 8;
        cvtA_k<<<(int)((t8 + 255) / 256), 256, 0, stream>>>(x, xf, t8);
        cvtWT_k<<<(C * d1 + 255) / 256, 256, 0, stream>>>(W1, w1t, C, d1);
        cvtWT_k<<<(d1 * d2 + 255) / 256, 256, 0, stream>>>(W2, w2t, d1, d2);
    }

    // ---- layer 1: 128 -> 256, ELU ----
    {
        dim3 g((N + 127) / 128, d1 / 64);
        gemm1_k<<<g, 256, 0, stream>>>((const ushort*)xf, (const ushort*)w1t,
                                       ch1, as1b, ad1b, as1, ad1, N, C, d1);
        agg1_k<<<wb, 256, 0, stream>>>(offsets, csr, as1b, ad1b, ch1, b1, o1, N);
    }
    // ---- layer 2: 256 -> 64, ELU, fused layer-3 prep ----
    {
        dim3 g((N + 127) / 128, d2 / 64);
        gemm2_k<<<g, 256, 0, stream>>>((const ushort*)o1, (const ushort*)w2t,
                                       ch2, as2b, ad2b, as2, ad2, N, d1, d2);
        agg2_k<<<wb, 256, 0, stream>>>(offsets, csr, as2b, ad2b, ch2, b2,
                                       W3, as3, ad3, h3, as3b, ad3b, N);
    }
    // ---- layer 3: aggregation ----
    agg3_k<<<wb, 256, 0, stream>>>(offsets, csr, as3b, ad3b, h3, b3, (float*)d_out, N);
}

// Round 10
// 341.010 us; speedup vs baseline: 1.1419x; 1.0167x over previous
//
#include <hip/hip_runtime.h>
#include <hip/hip_bf16.h>
#include <hip/hip_fp16.h>
#include <math.h>

#define NEG_SLOPE 0.2f

typedef __attribute__((ext_vector_type(8))) short      s16x8_t;
typedef __attribute__((ext_vector_type(8))) _Float16   f16x8_t;
typedef __attribute__((ext_vector_type(4))) float      f32x4_t;

struct __align__(8) half4_t { __half2 a, b; };

// ---------------------------------------------------------------------------
// prep0: zero accumulators + all fp32->fp16 converts in ONE kernel
// (replaces 2 memsets + 3 convert kernels; all phases independent)
// ---------------------------------------------------------------------------
__global__ __launch_bounds__(256) void prep0_k(
    int* __restrict__ cursor, float* __restrict__ alpha4, int n,
    const float* __restrict__ x, __half* __restrict__ xf, long xcnt8,
    const float* __restrict__ W1, __half* __restrict__ w1t, int K1, int N1,
    const float* __restrict__ W2, __half* __restrict__ w2t, int K2, int N2)
{
    const int gid = blockIdx.x * 256 + threadIdx.x;
    const int gsz = gridDim.x * 256;

    for (int i = gid; i < n; i += gsz) cursor[i] = 0;
    for (long i = gid; i < 4L * n; i += gsz) alpha4[i] = 0.f;
    for (long i = gid; i < xcnt8; i += gsz) {
        const float* src = x + i * 8;
        float4 a = *(const float4*)src;
        float4 b = *(const float4*)(src + 4);
        half4_t o0, o1;
        o0.a = __floats2half2_rn(a.x, a.y);
        o0.b = __floats2half2_rn(a.z, a.w);
        o1.a = __floats2half2_rn(b.x, b.y);
        o1.b = __floats2half2_rn(b.z, b.w);
        *(half4_t*)(xf + i * 8)     = o0;
        *(half4_t*)(xf + i * 8 + 4) = o1;
    }
    for (int i = gid; i < K1 * N1; i += gsz) {
        int k = i / N1, c = i - k * N1;
        w1t[(size_t)c * K1 + k] = __float2half(W1[i]);
    }
    for (int i = gid; i < K2 * N2; i += gsz) {
        int k = i / N2, c = i - k * N2;
        w2t[(size_t)c * K2 + k] = __float2half(W2[i]);
    }
}

// ---------------------------------------------------------------------------
// CSR build: histogram -> block scan -> scatter fill
// ---------------------------------------------------------------------------
__global__ void hist_k(const int* __restrict__ ei, int E, int n, int* __restrict__ deg) {
    int e = blockIdx.x * 256 + threadIdx.x;
    int ET = E + n;
    if (e >= ET) return;
    int d = (e < E) ? ei[E + e] : (e - E);
    atomicAdd(&deg[d], 1);
}

__global__ void scan1_k(const int* __restrict__ deg, int* __restrict__ incl,
                        int* __restrict__ bsums, int n) {
    __shared__ int s[256];
    int tid = threadIdx.x;
    int i = blockIdx.x * 256 + tid;
    int v = (i < n) ? deg[i] : 0;
    s[tid] = v;
    __syncthreads();
    for (int off = 1; off < 256; off <<= 1) {
        int t = (tid >= off) ? s[tid - off] : 0;
        __syncthreads();
        s[tid] += t;
        __syncthreads();
    }
    if (i < n) incl[i] = s[tid];
    if (tid == 255) bsums[blockIdx.x] = s[255];
}

__global__ void scan2_k(int* __restrict__ bsums, int nch) {
    __shared__ int s[256];
    int tid = threadIdx.x;
    int v = (tid < nch) ? bsums[tid] : 0;
    int orig = v;
    s[tid] = v;
    __syncthreads();
    for (int off = 1; off < 256; off <<= 1) {
        int t = (tid >= off) ? s[tid - off] : 0;
        __syncthreads();
        s[tid] += t;
        __syncthreads();
    }
    if (tid < nch) bsums[tid] = s[tid] - orig;  // exclusive
}

__global__ void scan3_k(int* __restrict__ offsets, int* __restrict__ cursor,
                        const int* __restrict__ bsums, int n, int total) {
    int i = blockIdx.x * 256 + threadIdx.x;
    if (i < n) {
        int excl = offsets[i] - cursor[i] + bsums[i >> 8];
        offsets[i] = excl;
        cursor[i]  = excl;
    }
    if (i == 0 && blockIdx.x == 0) offsets[n] = total;
}

__global__ void fill_k(const int* __restrict__ ei, int E, int n,
                       int* __restrict__ cursor, int* __restrict__ csr) {
    int e = blockIdx.x * 256 + threadIdx.x;
    int ET = E + n;
    if (e >= ET) return;
    int s, d;
    if (e < E) { s = ei[e]; d = ei[E + e]; }
    else       { s = e - E; d = e - E; }
    int pos = atomicAdd(&cursor[d], 1);
    csr[pos] = s;
}

// ---------------------------------------------------------------------------
// fp16 MFMA GEMM (1-term), fused attention-prep epilogue.
// A [M,K] fp16 row-major. BT [Nc,K] fp16 (transposed). fp32 MFMA accum.
// Writes Ch fp16 [M,Nc]; atomic-accumulates asb/adb = h·a_src / h·a_dst.
// block tile 128x64, 4 waves (2Mx2N), wave tile 64x32, BK=32.
// ---------------------------------------------------------------------------
__device__ __forceinline__ void gemm_core(const ushort* __restrict__ A,
                                          const ushort* __restrict__ BT,
                                          __half* __restrict__ Ch,
                                          float* __restrict__ asb,
                                          float* __restrict__ adb,
                                          const float* __restrict__ a_src,
                                          const float* __restrict__ a_dst,
                                          int M, int K, int Nc) {
    __shared__ __align__(16) ushort sA[128][40];
    __shared__ __align__(16) ushort sB[64][40];

    const int tid  = threadIdx.x;
    const int lane = tid & 63;
    const int wv   = tid >> 6;
    const int wm   = wv & 1, wn = wv >> 1;
    const int m0   = blockIdx.x << 7;
    const int n0   = blockIdx.y << 6;

    f32x4_t acc[4][2];
#pragma unroll
    for (int i = 0; i < 4; i++)
#pragma unroll
        for (int j = 0; j < 2; j++) acc[i][j] = (f32x4_t){0.f, 0.f, 0.f, 0.f};

    const int arow = tid >> 1;          // 0..127
    const int acb  = (tid & 1) << 4;    // 0 / 16
    const int brow = tid >> 2;          // 0..63
    const int bkb  = (tid & 3) << 3;    // 0,8,16,24

    const s16x8_t zv = {};

    for (int k0 = 0; k0 < K; k0 += 32) {
        {
            const int gr = m0 + arow;
            s16x8_t v0 = zv, v1 = zv;
            if (gr < M) {
                const ushort* pa = A + (size_t)gr * K + k0 + acb;
                v0 = *(const s16x8_t*)pa;
                v1 = *(const s16x8_t*)(pa + 8);
            }
            *(s16x8_t*)&sA[arow][acb]     = v0;
            *(s16x8_t*)&sA[arow][acb + 8] = v1;
        }
        {
            const ushort* pb = BT + (size_t)(n0 + brow) * K + k0 + bkb;
            *(s16x8_t*)&sB[brow][bkb] = *(const s16x8_t*)pb;
        }
        __syncthreads();
        f16x8_t af[4], bf[2];
        const int rbase = (wm << 6) + (lane & 15);
        const int slot  = (lane >> 4) << 3;
#pragma unroll
        for (int mi = 0; mi < 4; mi++)
            af[mi] = *(const f16x8_t*)&sA[rbase + (mi << 4)][slot];
        const int cbase = (wn << 5) + (lane & 15);
#pragma unroll
        for (int ni = 0; ni < 2; ni++)
            bf[ni] = *(const f16x8_t*)&sB[cbase + (ni << 4)][slot];
#pragma unroll
        for (int mi = 0; mi < 4; mi++)
#pragma unroll
            for (int ni = 0; ni < 2; ni++)
                acc[mi][ni] = __builtin_amdgcn_mfma_f32_16x16x32_f16(af[mi], bf[ni], acc[mi][ni], 0, 0, 0);
        __syncthreads();
    }

    // epilogue: C/D layout col=lane&15, row=(lane>>4)*4+reg
    const int col0 = n0 + (wn << 5) + (lane & 15);
    const float asv0 = a_src[col0],      adv0 = a_dst[col0];
    const float asv1 = a_src[col0 + 16], adv1 = a_dst[col0 + 16];

#pragma unroll
    for (int mi = 0; mi < 4; mi++) {
        const int row0 = m0 + (wm << 6) + (mi << 4) + ((lane >> 4) << 2);
#pragma unroll
        for (int ni = 0; ni < 2; ni++) {
            const int col = col0 + (ni << 4);
#pragma unroll
            for (int r = 0; r < 4; r++)
                if (row0 + r < M)
                    Ch[(size_t)(row0 + r) * Nc + col] = __float2half(acc[mi][ni][r]);
        }
        float ss[4], sd[4];
#pragma unroll
        for (int r = 0; r < 4; r++) {
            ss[r] = acc[mi][0][r] * asv0 + acc[mi][1][r] * asv1;
            sd[r] = acc[mi][0][r] * adv0 + acc[mi][1][r] * adv1;
        }
#pragma unroll
        for (int off = 1; off < 16; off <<= 1) {
#pragma unroll
            for (int r = 0; r < 4; r++) {
                ss[r] += __shfl_xor(ss[r], off);
                sd[r] += __shfl_xor(sd[r], off);
            }
        }
        if ((lane & 15) == 0) {
#pragma unroll
            for (int r = 0; r < 4; r++)
                if (row0 + r < M) {
                    atomicAdd(&asb[row0 + r], ss[r]);
                    atomicAdd(&adb[row0 + r], sd[r]);
                }
        }
    }
}

__global__ __launch_bounds__(256) void gemm1_k(const ushort* A, const ushort* BT,
                                               __half* Ch, float* asb, float* adb,
                                               const float* a_src, const float* a_dst,
                                               int M, int K, int Nc) {
    gemm_core(A, BT, Ch, asb, adb, a_src, a_dst, M, K, Nc);
}
__global__ __launch_bounds__(256) void gemm2_k(const ushort* A, const ushort* BT,
                                               __half* Ch, float* asb, float* adb,
                                               const float* a_src, const float* a_dst,
                                               int M, int K, int Nc) {
    gemm_core(A, BT, Ch, asb, adb, a_src, a_dst, M, K, Nc);
}

// ---------------------------------------------------------------------------
// fused per-node softmax + aggregation (wave per node), fp16 h gather.
// No max-subtraction (clamp +-60). Two passes: (weights+sum), (gather).
// OUT16: write fp16 (next GEMM's A = gather copy). L3F: fuse 64->1 matmul +
// layer-3 logit pieces.
// ---------------------------------------------------------------------------
#define DEG_CAP 128

template <int D, bool DO_ELU, bool OUT16, bool L3F>
__device__ __forceinline__ void agg_core(const int* __restrict__ offs,
                                         const int* __restrict__ csr,
                                         const float* __restrict__ asb,
                                         const float* __restrict__ adb,
                                         const __half* __restrict__ h,
                                         const float* __restrict__ bias,
                                         float* __restrict__ out,
                                         __half* __restrict__ o16,
                                         const float* __restrict__ W3,
                                         const float* __restrict__ as3,
                                         const float* __restrict__ ad3,
                                         float* __restrict__ h3o,
                                         float* __restrict__ as3b,
                                         float* __restrict__ ad3b, int n) {
    __shared__ float wsh[4][DEG_CAP];
    __shared__ int   osh[4][DEG_CAP];   // byte offsets j*D*2
    const int wv   = threadIdx.x >> 6;
    const int lane = threadIdx.x & 63;
    const int wid  = (blockIdx.x << 2) + wv;
    const bool active = wid < n;

    int beg = 0, deg = 0;
    float adi = 0.f;
    if (active) {
        beg = offs[wid];
        deg = offs[wid + 1] - beg;
        adi = adb[wid];
    }
    const int degc = deg < DEG_CAP ? deg : DEG_CAP;

    float inv = 0.f;
    if (active) {
        float ssum = 0.f;
        for (int e = lane; e < degc; e += 64) {
            int j = csr[beg + e];
            float v = asb[j] + adi;
            v = v > 0.f ? v : NEG_SLOPE * v;
            v = fminf(fmaxf(v, -60.f), 60.f);
            float w = __expf(v);
            osh[wv][e] = j * (int)(D * sizeof(__half));
            wsh[wv][e] = w;
            ssum += w;
        }
        for (int e = DEG_CAP + lane; e < deg; e += 64) {
            float v = asb[csr[beg + e]] + adi;
            v = v > 0.f ? v : NEG_SLOPE * v;
            v = fminf(fmaxf(v, -60.f), 60.f);
            ssum += __expf(v);
        }
#pragma unroll
        for (int o = 32; o; o >>= 1) ssum += __shfl_xor(ssum, o);
        inv = 1.f / ssum;
    }

    __syncthreads();

    if (!active) return;

    constexpr int U = D / 64;  // 4 (D=256) or 1 (D=64)
    float a0[U] = {}, a1[U] = {}, a2[U] = {}, a3[U] = {};
    const char* hb = (const char*)h + (U == 4 ? (lane << 3) : (lane << 1));

    int e = 0;
    for (; e + 4 <= degc; e += 4) {
        int o0 = osh[wv][e], o1 = osh[wv][e + 1], o2 = osh[wv][e + 2], o3 = osh[wv][e + 3];
        float w0 = wsh[wv][e], w1 = wsh[wv][e + 1], w2 = wsh[wv][e + 2], w3 = wsh[wv][e + 3];
        if constexpr (U == 4) {
            const half4_t h0 = *(const half4_t*)(hb + o0);
            const half4_t h1 = *(const half4_t*)(hb + o1);
            const half4_t h2 = *(const half4_t*)(hb + o2);
            const half4_t h3 = *(const half4_t*)(hb + o3);
            float2 f0a = __half22float2(h0.a), f0b = __half22float2(h0.b);
            float2 f1a = __half22float2(h1.a), f1b = __half22float2(h1.b);
            float2 f2a = __half22float2(h2.a), f2b = __half22float2(h2.b);
            float2 f3a = __half22float2(h3.a), f3b = __half22float2(h3.b);
            a0[0] = fmaf(w0, f0a.x, a0[0]); a0[1] = fmaf(w0, f0a.y, a0[1]);
            a0[2] = fmaf(w0, f0b.x, a0[2]); a0[3] = fmaf(w0, f0b.y, a0[3]);
            a1[0] = fmaf(w1, f1a.x, a1[0]); a1[1] = fmaf(w1, f1a.y, a1[1]);
            a1[2] = fmaf(w1, f1b.x, a1[2]); a1[3] = fmaf(w1, f1b.y, a1[3]);
            a2[0] = fmaf(w2, f2a.x, a2[0]); a2[1] = fmaf(w2, f2a.y, a2[1]);
            a2[2] = fmaf(w2, f2b.x, a2[2]); a2[3] = fmaf(w2, f2b.y, a2[3]);
            a3[0] = fmaf(w3, f3a.x, a3[0]); a3[1] = fmaf(w3, f3a.y, a3[1]);
            a3[2] = fmaf(w3, f3b.x, a3[2]); a3[3] = fmaf(w3, f3b.y, a3[3]);
        } else {
            a0[0] = fmaf(w0, __half2float(*(const __half*)(hb + o0)), a0[0]);
            a1[0] = fmaf(w1, __half2float(*(const __half*)(hb + o1)), a1[0]);
            a2[0] = fmaf(w2, __half2float(*(const __half*)(hb + o2)), a2[0]);
            a3[0] = fmaf(w3, __half2float(*(const __half*)(hb + o3)), a3[0]);
        }
    }
    for (; e < degc; ++e) {
        int o0 = osh[wv][e];
        float ww = wsh[wv][e];
        if constexpr (U == 4) {
            const half4_t hv = *(const half4_t*)(hb + o0);
            float2 fa = __half22float2(hv.a), fb = __half22float2(hv.b);
            a0[0] = fmaf(ww, fa.x, a0[0]); a0[1] = fmaf(ww, fa.y, a0[1]);
            a0[2] = fmaf(ww, fb.x, a0[2]); a0[3] = fmaf(ww, fb.y, a0[3]);
        } else {
            a0[0] = fmaf(ww, __half2float(*(const __half*)(hb + o0)), a0[0]);
        }
    }
    for (int eo = DEG_CAP; eo < deg; ++eo) {
        int j = csr[beg + eo];
        float v = asb[j] + adi;
        v = v > 0.f ? v : NEG_SLOPE * v;
        v = fminf(fmaxf(v, -60.f), 60.f);
        float ww = __expf(v);
        int o0 = j * (int)(D * sizeof(__half));
        if constexpr (U == 4) {
            const half4_t hv = *(const half4_t*)(hb + o0);
            float2 fa = __half22float2(hv.a), fb = __half22float2(hv.b);
            a0[0] = fmaf(ww, fa.x, a0[0]); a0[1] = fmaf(ww, fa.y, a0[1]);
            a0[2] = fmaf(ww, fb.x, a0[2]); a0[3] = fmaf(ww, fb.y, a0[3]);
        } else {
            a0[0] = fmaf(ww, __half2float(*(const __half*)(hb + o0)), a0[0]);
        }
    }

    if constexpr (U == 4) {
        float t[4];
#pragma unroll
        for (int u = 0; u < 4; u++) {
            float v = (a0[u] + a1[u] + a2[u] + a3[u]) * inv + bias[(lane << 2) + u];
            if (DO_ELU) v = v > 0.f ? v : expm1f(v);
            t[u] = v;
        }
        if constexpr (OUT16) {
            half4_t o;
            o.a = __floats2half2_rn(t[0], t[1]);
            o.b = __floats2half2_rn(t[2], t[3]);
            *(half4_t*)(o16 + (size_t)wid * D + (lane << 2)) = o;
        } else {
            *(float4*)(out + (size_t)wid * D + (lane << 2)) = make_float4(t[0], t[1], t[2], t[3]);
        }
    } else {
        float t = (a0[0] + a1[0] + a2[0] + a3[0]) * inv + bias[lane];
        if (DO_ELU) t = t > 0.f ? t : expm1f(t);
        if constexpr (L3F) {
            float c = t * W3[lane];
#pragma unroll
            for (int o = 32; o; o >>= 1) c += __shfl_xor(c, o);
            if (lane == 0) {
                h3o[wid]  = c;
                as3b[wid] = c * as3[0];
                ad3b[wid] = c * ad3[0];
            }
        } else {
            out[(size_t)wid * D + lane] = t;
        }
    }
}

__global__ __launch_bounds__(256) void agg1_k(const int* offs, const int* csr,
                                              const float* asb, const float* adb,
                                              const __half* h, const float* bias,
                                              __half* o16, int n) {
    agg_core<256, true, true, false>(offs, csr, asb, adb, h, bias,
                                     nullptr, o16,
                                     nullptr, nullptr, nullptr,
                                     nullptr, nullptr, nullptr, n);
}

__global__ __launch_bounds__(256) void agg2_k(const int* offs, const int* csr,
                                              const float* asb, const float* adb,
                                              const __half* h, const float* bias,
                                              const float* W3, const float* as3,
                                              const float* ad3, float* h3o,
                                              float* as3b, float* ad3b, int n) {
    agg_core<64, true, false, true>(offs, csr, asb, adb, h, bias,
                                    nullptr, nullptr,
                                    W3, as3, ad3, h3o, as3b, ad3b, n);
}

// ---------------------------------------------------------------------------
// layer 3 aggregation: single pass (no max, clamped exp)
// ---------------------------------------------------------------------------
__global__ void agg3_k(const int* __restrict__ offs, const int* __restrict__ csr,
                       const float* __restrict__ asb, const float* __restrict__ adb,
                       const float* __restrict__ h3, const float* __restrict__ b3,
                       float* __restrict__ out, int n) {
    int wid = (blockIdx.x << 2) + (threadIdx.x >> 6);
    int lane = threadIdx.x & 63;
    if (wid >= n) return;
    int beg = offs[wid], end = offs[wid + 1];
    float adi = adb[wid];

    float ssum = 0.f, acc = 0.f;
    for (int e = beg + lane; e < end; e += 64) {
        int j = csr[e];
        float v = asb[j] + adi;
        v = v > 0.f ? v : NEG_SLOPE * v;
        v = fminf(fmaxf(v, -60.f), 60.f);
        float w = __expf(v);
        ssum += w;
        acc = fmaf(w, h3[j], acc);
    }
#pragma unroll
    for (int o = 32; o; o >>= 1) {
        ssum += __shfl_xor(ssum, o);
        acc  += __shfl_xor(acc, o);
    }
    if (lane == 0) out[wid] = acc / ssum + b3[0];
}

// ---------------------------------------------------------------------------
extern "C" void kernel_launch(void* const* d_in, const int* in_sizes, int n_in,
                              void* d_out, int out_size, void* d_ws, size_t ws_size,
                              hipStream_t stream) {
    const float* x   = (const float*)d_in[0];
    const int*   ei  = (const int*)d_in[1];
    const float* W1  = (const float*)d_in[2];
    const float* as1 = (const float*)d_in[3];
    const float* ad1 = (const float*)d_in[4];
    const float* b1  = (const float*)d_in[5];
    const float* W2  = (const float*)d_in[6];
    const float* as2 = (const float*)d_in[7];
    const float* ad2 = (const float*)d_in[8];
    const float* b2  = (const float*)d_in[9];
    const float* W3  = (const float*)d_in[10];
    const float* as3 = (const float*)d_in[11];
    const float* ad3 = (const float*)d_in[12];
    const float* b3  = (const float*)d_in[13];

    const int d1 = in_sizes[3];                    // 256
    const int C  = in_sizes[2] / d1;               // 128
    const int N  = in_sizes[0] / C;                // 50000
    const int E  = in_sizes[1] / 2;                // 800000
    const int d2 = in_sizes[7];                    // 64
    const int ET = E + N;                          // 850000

    char* p = (char*)d_ws;
    auto alloc = [&](size_t bytes) -> void* {
        void* q = (void*)p;
        p += (bytes + 255) & ~(size_t)255;
        return q;
    };
    int*    offsets = (int*)alloc(sizeof(int) * (size_t)(N + 1));
    int*    cursor  = (int*)alloc(sizeof(int) * (size_t)N);
    int*    bsums   = (int*)alloc(sizeof(int) * 256);
    int*    csr     = (int*)alloc(sizeof(int) * (size_t)ET);
    float*  alpha   = (float*)alloc(sizeof(float) * (size_t)4 * N);  // as1b,ad1b,as2b,ad2b
    float*  as1b = alpha, *ad1b = alpha + N, *as2b = alpha + 2 * N, *ad2b = alpha + 3 * N;
    __half* xf      = (__half*)alloc(sizeof(__half) * (size_t)N * C);
    __half* w1t     = (__half*)alloc(sizeof(__half) * (size_t)C * d1);
    __half* w2t     = (__half*)alloc(sizeof(__half) * (size_t)d1 * d2);
    __half* ch1     = (__half*)alloc(sizeof(__half) * (size_t)N * d1);
    __half* o1      = (__half*)alloc(sizeof(__half) * (size_t)N * d1);
    __half* ch2     = (__half*)alloc(sizeof(__half) * (size_t)N * d2);
    float*  h3      = (float*)alloc(sizeof(float) * (size_t)N);
    float*  as3b    = (float*)alloc(sizeof(float) * (size_t)N);
    float*  ad3b    = (float*)alloc(sizeof(float) * (size_t)N);

    const int eb  = (ET + 255) / 256;
    const int nch = (N + 255) / 256;
    const int wb  = (N + 3) / 4;

    // ---- fused zero + converts (1 kernel, replaces 5 dispatches) ----
    {
        long t8 = (long)N * C / 8;
        prep0_k<<<2048, 256, 0, stream>>>(cursor, alpha, N,
                                          x, xf, t8,
                                          W1, w1t, C, d1,
                                          W2, w2t, d1, d2);
    }

    // ---- CSR build ----
    hist_k<<<eb, 256, 0, stream>>>(ei, E, N, cursor);
    scan1_k<<<nch, 256, 0, stream>>>(cursor, offsets, bsums, N);
    scan2_k<<<1, 256, 0, stream>>>(bsums, nch);
    scan3_k<<<nch, 256, 0, stream>>>(offsets, cursor, bsums, N, ET);
    fill_k<<<eb, 256, 0, stream>>>(ei, E, N, cursor, csr);

    // ---- layer 1: 128 -> 256, ELU ----
    {
        dim3 g((N + 127) / 128, d1 / 64);
        gemm1_k<<<g, 256, 0, stream>>>((const ushort*)xf, (const ushort*)w1t,
                                       ch1, as1b, ad1b, as1, ad1, N, C, d1);
        agg1_k<<<wb, 256, 0, stream>>>(offsets, csr, as1b, ad1b, ch1, b1, o1, N);
    }
    // ---- layer 2: 256 -> 64, ELU, fused layer-3 prep ----
    {
        dim3 g((N + 127) / 128, d2 / 64);
        gemm2_k<<<g, 256, 0, stream>>>((const ushort*)o1, (const ushort*)w2t,
                                       ch2, as2b, ad2b, as2, ad2, N, d1, d2);
        agg2_k<<<wb, 256, 0, stream>>>(offsets, csr, as2b, ad2b, ch2, b2,
                                       W3, as3, ad3, h3, as3b, ad3b, N);
    }
    // ---- layer 3: aggregation ----
    agg3_k<<<wb, 256, 0, stream>>>(offsets, csr, as3b, ad3b, h3, b3, (float*)d_out, N);
}